// Round 3
// baseline (10928.111 us; speedup 1.0000x reference)
//
#include <hip/hip_runtime.h>

#define T_LEN 2048
#define BSZ 4
#define NHEAD 16
#define DHEAD 64
#define DMODEL 1024
#define SCALE 0.125f

typedef __bf16 bf16x8 __attribute__((ext_vector_type(8)));
typedef float f32x4 __attribute__((ext_vector_type(4)));

__device__ __forceinline__ float bf2f(unsigned short u) {
  union { unsigned int i; float f; } v; v.i = ((unsigned int)u) << 16; return v.f;
}
__device__ __forceinline__ unsigned short f2bf(float f) {
  union { float f; unsigned int i; } v; v.f = f;
  unsigned int r = v.i + 0x7fffu + ((v.i >> 16) & 1u);   // RNE
  return (unsigned short)(r >> 16);
}

typedef __attribute__((address_space(1))) void* gptr_t;
typedef __attribute__((address_space(3))) void* lptr_t;

__device__ __forceinline__ void load_lds16(const void* g, void* l) {
  __builtin_amdgcn_global_load_lds((gptr_t)g, (lptr_t)l, 16, 0, 0);
}

// fp32 -> bf16 elementwise, n multiple of 4
__global__ __launch_bounds__(256) void cvt_kernel(const float* __restrict__ in,
                                                  unsigned short* __restrict__ out, int n) {
  const int i = (blockIdx.x * 256 + threadIdx.x) * 4;
  if (i < n) {
    const float4 v = *(const float4*)(in + i);
    ushort4 o;
    o.x = f2bf(v.x); o.y = f2bf(v.y); o.z = f2bf(v.z); o.w = f2bf(v.w);
    *(ushort4*)(out + i) = o;
  }
}

// Decide mask layout: numpy bool (1 byte/elem) vs int32 (4 bytes/elem, values 0/1).
// If every byte at index%4!=0 within the first 8192 bytes is zero -> int32 layout.
__global__ void detect_mask(const unsigned char* __restrict__ mask, int* __restrict__ flag) {
  __shared__ int any;
  if (threadIdx.x == 0) any = 0;
  __syncthreads();
  int acc = 0;
  for (int i = threadIdx.x; i < T_LEN * BSZ; i += 256)
    if ((i & 3) != 0 && mask[i] != 0) acc = 1;
  if (acc) atomicOr(&any, 1);
  __syncthreads();
  if (threadIdx.x == 0) *flag = any ? 0 : 1;   // 1 => int32 layout, 0 => byte layout
}

// C = A(MxK) * B^T(NxK), bf16 in, fp32 accum. 128x128 tile, BK=32, 4 waves.
// MODE 0: scatter bf16 -> outA as Q[b][n][i][d]
// MODE 1: scatter bf16 -> outA=K / outB=V as [b][n][j][d] (split at col 1024)
// MODE 2: plain fp32 row-major -> outF (M x DMODEL)
template<int MODE>
__global__ __launch_bounds__(256) void gemm_bt(const unsigned short* __restrict__ A,
                                               const unsigned short* __restrict__ Bw,
                                               unsigned short* __restrict__ outA,
                                               unsigned short* __restrict__ outB,
                                               float* __restrict__ outF,
                                               int K) {
  __shared__ alignas(16) unsigned short As[128 * 32];
  __shared__ alignas(16) unsigned short Bs[128 * 32];
  const int tid  = threadIdx.x;
  const int lane = tid & 63;
  const int wv   = tid >> 6;
  const int m0 = blockIdx.y * 128;
  const int n0 = blockIdx.x * 128;
  const int wr = (wv >> 1) * 64;
  const int wc = (wv & 1) * 64;
  const int mi   = lane & 15;
  const int quad = lane >> 4;

  f32x4 acc[4][4] = {};

  const int rowq = tid >> 2;
  const int kg   = (tid & 3) * 8;
  const unsigned short* Ag0 = A  + (size_t)(m0 + rowq) * K + kg;
  const unsigned short* Ag1 = Ag0 + (size_t)64 * K;
  const unsigned short* Bg0 = Bw + (size_t)(n0 + rowq) * K + kg;
  const unsigned short* Bg1 = Bg0 + (size_t)64 * K;
  unsigned short* AsW0 = As + wv * 512;          // wave-uniform LDS bases
  unsigned short* AsW1 = As + 2048 + wv * 512;
  unsigned short* BsW0 = Bs + wv * 512;
  unsigned short* BsW1 = Bs + 2048 + wv * 512;

  for (int k0 = 0; k0 < K; k0 += 32) {
    load_lds16(Ag0 + k0, AsW0);
    load_lds16(Ag1 + k0, AsW1);
    load_lds16(Bg0 + k0, BsW0);
    load_lds16(Bg1 + k0, BsW1);
    __syncthreads();
    bf16x8 af[4], bfr[4];
#pragma unroll
    for (int rt = 0; rt < 4; rt++)
      af[rt] = *(const bf16x8*)(As + (wr + rt * 16 + mi) * 32 + quad * 8);
#pragma unroll
    for (int ct = 0; ct < 4; ct++)
      bfr[ct] = *(const bf16x8*)(Bs + (wc + ct * 16 + mi) * 32 + quad * 8);
#pragma unroll
    for (int rt = 0; rt < 4; rt++)
#pragma unroll
      for (int ct = 0; ct < 4; ct++)
        acc[rt][ct] = __builtin_amdgcn_mfma_f32_16x16x32_bf16(af[rt], bfr[ct], acc[rt][ct], 0, 0, 0);
    __syncthreads();
  }

#pragma unroll
  for (int rt = 0; rt < 4; rt++) {
#pragma unroll
    for (int ct = 0; ct < 4; ct++) {
#pragma unroll
      for (int r = 0; r < 4; r++) {
        const int gm = m0 + wr + rt * 16 + quad * 4 + r;  // C/D: row = quad*4+reg
        const int gn = n0 + wc + ct * 16 + mi;            //      col = lane&15
        const float v = acc[rt][ct][r];
        if (MODE == 0) {
          const int i = gm >> 2, b = gm & 3, hn = gn >> 6, d = gn & 63;
          outA[(((size_t)b * NHEAD + hn) * T_LEN + i) * DHEAD + d] = f2bf(v);
        } else if (MODE == 1) {
          const int i = gm >> 2, b = gm & 3;
          if (gn < DMODEL) {
            const int hn = gn >> 6, d = gn & 63;
            outA[(((size_t)b * NHEAD + hn) * T_LEN + i) * DHEAD + d] = f2bf(v);
          } else {
            const int gn2 = gn - DMODEL, hn = gn2 >> 6, d = gn2 & 63;
            outB[(((size_t)b * NHEAD + hn) * T_LEN + i) * DHEAD + d] = f2bf(v);
          }
        } else {
          outF[(size_t)gm * DMODEL + gn] = v;
        }
      }
    }
  }
}

// Flash attention. grid (T/32, B, NH), 256 thr = 4 waves, 8 query rows/wave.
__global__ __launch_bounds__(256) void attn_kernel(const unsigned short* __restrict__ Qb,
                                                   const unsigned short* __restrict__ Kb,
                                                   const unsigned short* __restrict__ Vb,
                                                   const unsigned char* __restrict__ mask,
                                                   const int* __restrict__ mflag,
                                                   unsigned short* __restrict__ av) {
  __shared__ float Qs[32 * 64];
  __shared__ float Ks[64 * 65];
  __shared__ float Vs[64 * 65];
  __shared__ float Ps[4 * 64];
  __shared__ int   Ms[64];

  const int tid  = threadIdx.x;
  const int lane = tid & 63;
  const int wv   = tid >> 6;
  const int i0 = blockIdx.x * 32;
  const int b  = blockIdx.y;
  const int n  = blockIdx.z;
  const int hb = b * NHEAD + n;
  const size_t kvbase = (size_t)hb * T_LEN * DHEAD;
  const int mmode = *mflag;   // 1 => int32 mask, 0 => byte mask

  for (int idx = tid; idx < 32 * 64; idx += 256)
    Qs[idx] = SCALE * bf2f(Qb[kvbase + (size_t)i0 * DHEAD + idx]);

  float m_r[8], l_r[8], o_r[8];
#pragma unroll
  for (int r = 0; r < 8; r++) { m_r[r] = -1e30f; l_r[r] = 0.f; o_r[r] = 0.f; }

  for (int j0 = 0; j0 < T_LEN; j0 += 64) {
    for (int idx = tid; idx < 64 * 32; idx += 256) {
      const int j = idx >> 5, dp = (idx & 31) * 2;
      const size_t gb = kvbase + (size_t)(j0 + j) * DHEAD + dp;
      const ushort2 kk = *(const ushort2*)(Kb + gb);
      const ushort2 vvv = *(const ushort2*)(Vb + gb);
      Ks[j * 65 + dp] = bf2f(kk.x); Ks[j * 65 + dp + 1] = bf2f(kk.y);
      Vs[j * 65 + dp] = bf2f(vvv.x); Vs[j * 65 + dp + 1] = bf2f(vvv.y);
    }
    if (tid < 64) {
      const int j = j0 + tid;
      Ms[tid] = mmode ? ((const int*)mask)[(size_t)j * BSZ + b]
                      : (int)mask[(size_t)j * BSZ + b];
    }
    __syncthreads();
#pragma unroll
    for (int r = 0; r < 8; r++) {
      const float* qrow = Qs + (wv * 8 + r) * 64;
      const float* krow = Ks + lane * 65;
      float s = 0.f;
#pragma unroll
      for (int d = 0; d < 64; d++) s = fmaf(qrow[d], krow[d], s);
      const bool masked = (Ms[lane] != 0);
      s = masked ? -1e30f : s;
      float cm = s;
#pragma unroll
      for (int off = 32; off; off >>= 1) cm = fmaxf(cm, __shfl_xor(cm, off, 64));
      const float m_new = fmaxf(m_r[r], cm);
      const float p = masked ? 0.f : __expf(s - m_new);
      float ps = p;
#pragma unroll
      for (int off = 32; off; off >>= 1) ps += __shfl_xor(ps, off, 64);
      const float alpha = __expf(m_r[r] - m_new);
      l_r[r] = l_r[r] * alpha + ps;
      m_r[r] = m_new;
      Ps[wv * 64 + lane] = p;
      float o = o_r[r] * alpha;
      const float* pp   = Ps + wv * 64;
      const float* vcol = Vs + lane;
#pragma unroll
      for (int l2 = 0; l2 < 64; l2++) o = fmaf(pp[l2], vcol[l2 * 65], o);
      o_r[r] = o;
    }
    __syncthreads();
  }
#pragma unroll
  for (int r = 0; r < 8; r++) {
    const int i = i0 + wv * 8 + r;
    const float linv = (l_r[r] > 0.f) ? (1.f / l_r[r]) : 0.f;
    const float o = o_r[r] * linv;
    av[((size_t)i * BSZ + b) * DMODEL + n * DHEAD + lane] = f2bf(o);
  }
}

// out = LayerNorm(h + attn_out) * g + b  — fp32 in, fp32 out
__global__ __launch_bounds__(256) void ln_kernel(const float* __restrict__ h,
                                                 const float* __restrict__ ao,
                                                 const float* __restrict__ g,
                                                 const float* __restrict__ bb,
                                                 float* __restrict__ out) {
  __shared__ float red[16];
  const int row = blockIdx.x;
  const int tid = threadIdx.x;
  const size_t base = (size_t)row * DMODEL;
  float x[4];
  float s = 0.f, sq = 0.f;
#pragma unroll
  for (int k = 0; k < 4; k++) {
    const int c = tid + k * 256;
    const float xv = h[base + c] + ao[base + c];
    x[k] = xv; s += xv; sq += xv * xv;
  }
#pragma unroll
  for (int off = 32; off; off >>= 1) { s += __shfl_xor(s, off, 64); sq += __shfl_xor(sq, off, 64); }
  const int wv = tid >> 6, lane = tid & 63;
  if (lane == 0) { red[wv] = s; red[8 + wv] = sq; }
  __syncthreads();
  if (tid == 0) {
    float ts = 0.f, tq = 0.f;
    for (int w = 0; w < 4; w++) { ts += red[w]; tq += red[8 + w]; }
    red[4] = ts; red[12] = tq;
  }
  __syncthreads();
  const float mu  = red[4] * (1.f / DMODEL);
  const float var = red[12] * (1.f / DMODEL) - mu * mu;
  const float inv = rsqrtf(var + 1e-5f);
#pragma unroll
  for (int k = 0; k < 4; k++) {
    const int c = tid + k * 256;
    out[base + c] = (x[k] - mu) * inv * g[c] + bb[c];
  }
}

extern "C" void kernel_launch(void* const* d_in, const int* in_sizes, int n_in,
                              void* d_out, int out_size, void* d_ws, size_t ws_size,
                              hipStream_t stream) {
  (void)in_sizes; (void)n_in; (void)out_size; (void)ws_size;
  const float* h           = (const float*)d_in[0];
  const unsigned char* msk = (const unsigned char*)d_in[1];
  const float* wq          = (const float*)d_in[2];
  const float* wkv         = (const float*)d_in[3];
  const float* wo          = (const float*)d_in[4];
  const float* lng         = (const float*)d_in[5];
  const float* lnb         = (const float*)d_in[6];
  float* out = (float*)d_out;

  const size_t E  = (size_t)T_LEN * BSZ * DMODEL;        // 8.39M
  const size_t WQ = (size_t)NHEAD * DHEAD * DMODEL;      // 1.05M
  char* ws = (char*)d_ws;
  int* mflag            = (int*)ws;                       ws += 16;
  unsigned short* h_bf  = (unsigned short*)ws;            ws += E * 2;
  unsigned short* wq_bf = (unsigned short*)ws;            ws += WQ * 2;
  unsigned short* wkv_bf= (unsigned short*)ws;            ws += 2 * WQ * 2;
  unsigned short* wo_bf = (unsigned short*)ws;            ws += WQ * 2;
  unsigned short* Qb    = (unsigned short*)ws;            ws += E * 2;
  unsigned short* Kb    = (unsigned short*)ws;            ws += E * 2;
  unsigned short* Vb    = (unsigned short*)ws;            ws += E * 2;
  unsigned short* AV    = (unsigned short*)ws;            ws += E * 2;
  float* AO             = (float*)ws;

  const dim3 blk(256);
  detect_mask<<<1, blk, 0, stream>>>(msk, mflag);
  cvt_kernel<<<dim3((int)(E / 1024)), blk, 0, stream>>>(h, h_bf, (int)E);
  cvt_kernel<<<dim3((int)(WQ / 1024)), blk, 0, stream>>>(wq, wq_bf, (int)WQ);
  cvt_kernel<<<dim3((int)(2 * WQ / 1024)), blk, 0, stream>>>(wkv, wkv_bf, (int)(2 * WQ));
  cvt_kernel<<<dim3((int)(WQ / 1024)), blk, 0, stream>>>(wo, wo_bf, (int)WQ);

  gemm_bt<0><<<dim3(DMODEL / 128, T_LEN * BSZ / 128), blk, 0, stream>>>(h_bf, wq_bf, Qb, nullptr, nullptr, DMODEL);
  gemm_bt<1><<<dim3(2 * DMODEL / 128, T_LEN * BSZ / 128), blk, 0, stream>>>(h_bf, wkv_bf, Kb, Vb, nullptr, DMODEL);
  attn_kernel<<<dim3(T_LEN / 32, BSZ, NHEAD), blk, 0, stream>>>(Qb, Kb, Vb, msk, mflag, AV);
  gemm_bt<2><<<dim3(DMODEL / 128, T_LEN * BSZ / 128), blk, 0, stream>>>(AV, wo_bf, nullptr, nullptr, AO, DMODEL);
  ln_kernel<<<dim3(T_LEN * BSZ), blk, 0, stream>>>(h, AO, lng, lnb, out);
}

// Round 4
// 540.596 us; speedup vs baseline: 20.2149x; 20.2149x over previous
//
#include <hip/hip_runtime.h>

#define T_LEN 2048
#define BSZ 4
#define NHEAD 16
#define DHEAD 64
#define DMODEL 1024
#define SCALE 0.125f
#define ROW 72   // padded LDS row stride in bf16 (16B-aligned rows, conflict-free b128)

typedef __bf16 bf16x8 __attribute__((ext_vector_type(8)));
typedef float f32x4 __attribute__((ext_vector_type(4)));

__device__ __forceinline__ float bf2f(unsigned short u) {
  union { unsigned int i; float f; } v; v.i = ((unsigned int)u) << 16; return v.f;
}
__device__ __forceinline__ unsigned short f2bf(float f) {
  union { float f; unsigned int i; } v; v.f = f;
  unsigned int r = v.i + 0x7fffu + ((v.i >> 16) & 1u);   // RNE
  return (unsigned short)(r >> 16);
}

typedef __attribute__((address_space(1))) void* gptr_t;
typedef __attribute__((address_space(3))) void* lptr_t;

__device__ __forceinline__ void load_lds16(const void* g, void* l) {
  __builtin_amdgcn_global_load_lds((gptr_t)g, (lptr_t)l, 16, 0, 0);
}

// fp32 -> bf16 elementwise, n multiple of 4
__global__ __launch_bounds__(256) void cvt_kernel(const float* __restrict__ in,
                                                  unsigned short* __restrict__ out, int n) {
  const int i = (blockIdx.x * 256 + threadIdx.x) * 4;
  if (i < n) {
    const float4 v = *(const float4*)(in + i);
    ushort4 o;
    o.x = f2bf(v.x); o.y = f2bf(v.y); o.z = f2bf(v.z); o.w = f2bf(v.w);
    *(ushort4*)(out + i) = o;
  }
}

// mask layout detect: numpy bool (1B) vs int32. int32 => bytes at idx%4!=0 all zero.
__global__ void detect_mask(const unsigned char* __restrict__ mask, int* __restrict__ flag) {
  __shared__ int any;
  if (threadIdx.x == 0) any = 0;
  __syncthreads();
  int acc = 0;
  for (int i = threadIdx.x; i < T_LEN * BSZ; i += 256)
    if ((i & 3) != 0 && mask[i] != 0) acc = 1;
  if (acc) atomicOr(&any, 1);
  __syncthreads();
  if (threadIdx.x == 0) *flag = any ? 0 : 1;   // 1 => int32, 0 => byte
}

// C = A(MxK) * B^T(NxK), bf16 in, fp32 accum. 128x128 tile, BK=32, 4 waves.
// MODE 0: scatter bf16 -> outA as Q[b][n][i][d]
// MODE 1: scatter bf16 -> outA=K[b][n][j][d]; outB = V TRANSPOSED [b][n][d][j]
// MODE 2: plain fp32 row-major -> outF (M x DMODEL)
template<int MODE>
__global__ __launch_bounds__(256) void gemm_bt(const unsigned short* __restrict__ A,
                                               const unsigned short* __restrict__ Bw,
                                               unsigned short* __restrict__ outA,
                                               unsigned short* __restrict__ outB,
                                               float* __restrict__ outF,
                                               int K) {
  __shared__ alignas(16) unsigned short As[128 * 32];
  __shared__ alignas(16) unsigned short Bs[128 * 32];
  const int tid  = threadIdx.x;
  const int lane = tid & 63;
  const int wv   = tid >> 6;
  const int m0 = blockIdx.y * 128;
  const int n0 = blockIdx.x * 128;
  const int wr = (wv >> 1) * 64;
  const int wc = (wv & 1) * 64;
  const int mi   = lane & 15;
  const int quad = lane >> 4;

  f32x4 acc[4][4] = {};

  const int rowq = tid >> 2;
  const int kg   = (tid & 3) * 8;
  const unsigned short* Ag0 = A  + (size_t)(m0 + rowq) * K + kg;
  const unsigned short* Ag1 = Ag0 + (size_t)64 * K;
  const unsigned short* Bg0 = Bw + (size_t)(n0 + rowq) * K + kg;
  const unsigned short* Bg1 = Bg0 + (size_t)64 * K;
  unsigned short* AsW0 = As + wv * 512;
  unsigned short* AsW1 = As + 2048 + wv * 512;
  unsigned short* BsW0 = Bs + wv * 512;
  unsigned short* BsW1 = Bs + 2048 + wv * 512;

  for (int k0 = 0; k0 < K; k0 += 32) {
    load_lds16(Ag0 + k0, AsW0);
    load_lds16(Ag1 + k0, AsW1);
    load_lds16(Bg0 + k0, BsW0);
    load_lds16(Bg1 + k0, BsW1);
    __syncthreads();
    bf16x8 af[4], bfr[4];
#pragma unroll
    for (int rt = 0; rt < 4; rt++)
      af[rt] = *(const bf16x8*)(As + (wr + rt * 16 + mi) * 32 + quad * 8);
#pragma unroll
    for (int ct = 0; ct < 4; ct++)
      bfr[ct] = *(const bf16x8*)(Bs + (wc + ct * 16 + mi) * 32 + quad * 8);
#pragma unroll
    for (int rt = 0; rt < 4; rt++)
#pragma unroll
      for (int ct = 0; ct < 4; ct++)
        acc[rt][ct] = __builtin_amdgcn_mfma_f32_16x16x32_bf16(af[rt], bfr[ct], acc[rt][ct], 0, 0, 0);
    __syncthreads();
  }

#pragma unroll
  for (int rt = 0; rt < 4; rt++) {
#pragma unroll
    for (int ct = 0; ct < 4; ct++) {
#pragma unroll
      for (int r = 0; r < 4; r++) {
        const int gm = m0 + wr + rt * 16 + quad * 4 + r;  // C/D: row = quad*4+reg
        const int gn = n0 + wc + ct * 16 + mi;            //      col = lane&15
        const float v = acc[rt][ct][r];
        if (MODE == 0) {
          const int i = gm >> 2, b = gm & 3, hn = gn >> 6, d = gn & 63;
          outA[(((size_t)b * NHEAD + hn) * T_LEN + i) * DHEAD + d] = f2bf(v);
        } else if (MODE == 1) {
          const int i = gm >> 2, b = gm & 3;
          if (gn < DMODEL) {
            const int hn = gn >> 6, d = gn & 63;
            outA[(((size_t)b * NHEAD + hn) * T_LEN + i) * DHEAD + d] = f2bf(v);
          } else {
            const int gn2 = gn - DMODEL, hn = gn2 >> 6, d = gn2 & 63;
            // V stored TRANSPOSED: [b][n][d][t]
            outB[(((size_t)b * NHEAD + hn) * DHEAD + d) * T_LEN + i] = f2bf(v);
          }
        } else {
          outF[(size_t)gm * DMODEL + gn] = v;
        }
      }
    }
  }
}

// MFMA flash attention. grid (T/64, B, NH), 256 thr = 4 waves x 16 q-rows.
// K chunk = 64 keys. Q,K row-major [t][d]; V transposed [d][t] (all bf16).
__global__ __launch_bounds__(256) void attn_mfma(const unsigned short* __restrict__ Qg,
                                                 const unsigned short* __restrict__ Kg,
                                                 const unsigned short* __restrict__ Vtg,
                                                 const unsigned char* __restrict__ mask,
                                                 const int* __restrict__ mflag,
                                                 unsigned short* __restrict__ av) {
  // smem layout (ushorts): Ks[0,4608) Vts[4608,9216) Qs/Ps[9216,13824) Ms@13824
  __shared__ alignas(16) unsigned short smem[13952];
  unsigned short* Ks  = smem;
  unsigned short* Vts = smem + 4608;
  unsigned short* Qs  = smem + 9216;   // aliased with Ps after qa frags are loaded
  unsigned short* Ps  = smem + 9216;
  int* Ms = (int*)(smem + 13824);

  const int tid  = threadIdx.x;
  const int lane = tid & 63;
  const int wv   = tid >> 6;
  const int mi   = lane & 15;
  const int quad = lane >> 4;
  const int i0 = blockIdx.x * 64;
  const int b  = blockIdx.y;
  const int n  = blockIdx.z;
  const size_t base = ((size_t)b * NHEAD + n) * T_LEN * DHEAD;
  const int mmode = *mflag;

  // stage Q tile (64x64 bf16) into Qs
  for (int it = tid; it < 512; it += 256) {
    const int r = it >> 3, c8 = (it & 7) * 8;
    *(uint4*)(Qs + r * ROW + c8) = *(const uint4*)(Qg + base + (size_t)(i0 + r) * DHEAD + c8);
  }
  __syncthreads();
  bf16x8 qa[2];
  qa[0] = *(const bf16x8*)(Qs + (wv * 16 + mi) * ROW + quad * 8);
  qa[1] = *(const bf16x8*)(Qs + (wv * 16 + mi) * ROW + 32 + quad * 8);
  // (Qs is dead after this point; first in-loop __syncthreads makes aliasing Ps safe)

  float m_st[4], l_st[4];
  f32x4 oc[4] = {};
#pragma unroll
  for (int r = 0; r < 4; r++) { m_st[r] = -1e30f; l_st[r] = 0.f; }

  unsigned short* PsW = Ps + wv * 16 * ROW / 1;   // per-wave P region? see below
  // per-wave P region: 16 rows x ROW, waves packed: wv * 16 * ROW would exceed 4608.
  // Instead each wave uses 16*ROW=1152 ushorts: 4 waves = 4608 exactly.
  PsW = Ps + wv * 1152;

  for (int j0 = 0; j0 < T_LEN; j0 += 64) {
    // stage K (row-major) and Vt (d-major) chunks
    for (int it = tid; it < 512; it += 256) {
      const int r = it >> 3, c8 = (it & 7) * 8;
      *(uint4*)(Ks  + r * ROW + c8) = *(const uint4*)(Kg  + base + (size_t)(j0 + r) * DHEAD + c8);
      *(uint4*)(Vts + r * ROW + c8) = *(const uint4*)(Vtg + base + (size_t)r * T_LEN + j0 + c8);
    }
    if (tid < 64)
      Ms[tid] = mmode ? ((const int*)mask)[(size_t)(j0 + tid) * BSZ + b]
                      : (int)mask[(size_t)(j0 + tid) * BSZ + b];
    __syncthreads();

    // S = Q K^T  (per wave: 16 q-rows x 64 keys)
    f32x4 sc[4] = {};
#pragma unroll
    for (int ct = 0; ct < 4; ct++) {
      const bf16x8 kf0 = *(const bf16x8*)(Ks + (ct * 16 + mi) * ROW + quad * 8);
      const bf16x8 kf1 = *(const bf16x8*)(Ks + (ct * 16 + mi) * ROW + 32 + quad * 8);
      sc[ct] = __builtin_amdgcn_mfma_f32_16x16x32_bf16(qa[0], kf0, sc[ct], 0, 0, 0);
      sc[ct] = __builtin_amdgcn_mfma_f32_16x16x32_bf16(qa[1], kf1, sc[ct], 0, 0, 0);
    }
    bool mk[4];
#pragma unroll
    for (int ct = 0; ct < 4; ct++) mk[ct] = (Ms[ct * 16 + mi] != 0);
#pragma unroll
    for (int ct = 0; ct < 4; ct++)
#pragma unroll
      for (int r = 0; r < 4; r++)
        sc[ct][r] = mk[ct] ? -1e30f : sc[ct][r] * SCALE;

    // online softmax (per-lane rows: quad*4+r; cols spread over quad's 16 lanes x 4 ct)
    float mnew[4], alpha[4], rs[4];
#pragma unroll
    for (int r = 0; r < 4; r++) {
      float v = fmaxf(fmaxf(sc[0][r], sc[1][r]), fmaxf(sc[2][r], sc[3][r]));
      v = fmaxf(v, __shfl_xor(v, 1, 64));
      v = fmaxf(v, __shfl_xor(v, 2, 64));
      v = fmaxf(v, __shfl_xor(v, 4, 64));
      v = fmaxf(v, __shfl_xor(v, 8, 64));
      mnew[r] = fmaxf(m_st[r], v);
      alpha[r] = __expf(m_st[r] - mnew[r]);
      m_st[r] = mnew[r];
      rs[r] = 0.f;
    }
#pragma unroll
    for (int ct = 0; ct < 4; ct++)
#pragma unroll
      for (int r = 0; r < 4; r++) {
        const float p = mk[ct] ? 0.f : __expf(sc[ct][r] - mnew[r]);
        sc[ct][r] = p;
        rs[r] += p;
      }
#pragma unroll
    for (int r = 0; r < 4; r++) {
      float s = rs[r];
      s += __shfl_xor(s, 1, 64);
      s += __shfl_xor(s, 2, 64);
      s += __shfl_xor(s, 4, 64);
      s += __shfl_xor(s, 8, 64);
      l_st[r] = l_st[r] * alpha[r] + s;
    }
    // write P (C-layout) to LDS as bf16, re-read as A-operand fragments
#pragma unroll
    for (int ct = 0; ct < 4; ct++)
#pragma unroll
      for (int r = 0; r < 4; r++)
        PsW[(quad * 4 + r) * ROW + ct * 16 + mi] = f2bf(sc[ct][r]);
#pragma unroll
    for (int ct = 0; ct < 4; ct++)
#pragma unroll
      for (int r = 0; r < 4; r++)
        oc[ct][r] *= alpha[r];
    const bf16x8 pa0 = *(const bf16x8*)(PsW + mi * ROW + quad * 8);
    const bf16x8 pa1 = *(const bf16x8*)(PsW + mi * ROW + 32 + quad * 8);
#pragma unroll
    for (int ct = 0; ct < 4; ct++) {
      const bf16x8 vf0 = *(const bf16x8*)(Vts + (ct * 16 + mi) * ROW + quad * 8);
      const bf16x8 vf1 = *(const bf16x8*)(Vts + (ct * 16 + mi) * ROW + 32 + quad * 8);
      oc[ct] = __builtin_amdgcn_mfma_f32_16x16x32_bf16(pa0, vf0, oc[ct], 0, 0, 0);
      oc[ct] = __builtin_amdgcn_mfma_f32_16x16x32_bf16(pa1, vf1, oc[ct], 0, 0, 0);
    }
    __syncthreads();
  }

  float linv[4];
#pragma unroll
  for (int r = 0; r < 4; r++) linv[r] = (l_st[r] > 0.f) ? (1.f / l_st[r]) : 0.f;
#pragma unroll
  for (int ct = 0; ct < 4; ct++)
#pragma unroll
    for (int r = 0; r < 4; r++) {
      const int q = i0 + wv * 16 + quad * 4 + r;
      const int d = ct * 16 + mi;
      av[((size_t)q * BSZ + b) * DMODEL + n * DHEAD + d] = f2bf(oc[ct][r] * linv[r]);
    }
}

// out = LayerNorm(h + attn_out) * g + b  — fp32 in, fp32 out
__global__ __launch_bounds__(256) void ln_kernel(const float* __restrict__ h,
                                                 const float* __restrict__ ao,
                                                 const float* __restrict__ g,
                                                 const float* __restrict__ bb,
                                                 float* __restrict__ out) {
  __shared__ float red[16];
  const int row = blockIdx.x;
  const int tid = threadIdx.x;
  const size_t base = (size_t)row * DMODEL;
  float x[4];
  float s = 0.f, sq = 0.f;
#pragma unroll
  for (int k = 0; k < 4; k++) {
    const int c = tid + k * 256;
    const float xv = h[base + c] + ao[base + c];
    x[k] = xv; s += xv; sq += xv * xv;
  }
#pragma unroll
  for (int off = 32; off; off >>= 1) { s += __shfl_xor(s, off, 64); sq += __shfl_xor(sq, off, 64); }
  const int wv = tid >> 6, lane = tid & 63;
  if (lane == 0) { red[wv] = s; red[8 + wv] = sq; }
  __syncthreads();
  if (tid == 0) {
    float ts = 0.f, tq = 0.f;
    for (int w = 0; w < 4; w++) { ts += red[w]; tq += red[8 + w]; }
    red[4] = ts; red[12] = tq;
  }
  __syncthreads();
  const float mu  = red[4] * (1.f / DMODEL);
  const float var = red[12] * (1.f / DMODEL) - mu * mu;
  const float inv = rsqrtf(var + 1e-5f);
#pragma unroll
  for (int k = 0; k < 4; k++) {
    const int c = tid + k * 256;
    out[base + c] = (x[k] - mu) * inv * g[c] + bb[c];
  }
}

extern "C" void kernel_launch(void* const* d_in, const int* in_sizes, int n_in,
                              void* d_out, int out_size, void* d_ws, size_t ws_size,
                              hipStream_t stream) {
  (void)in_sizes; (void)n_in; (void)out_size; (void)ws_size;
  const float* h           = (const float*)d_in[0];
  const unsigned char* msk = (const unsigned char*)d_in[1];
  const float* wq          = (const float*)d_in[2];
  const float* wkv         = (const float*)d_in[3];
  const float* wo          = (const float*)d_in[4];
  const float* lng         = (const float*)d_in[5];
  const float* lnb         = (const float*)d_in[6];
  float* out = (float*)d_out;

  const size_t E  = (size_t)T_LEN * BSZ * DMODEL;        // 8.39M
  const size_t WQ = (size_t)NHEAD * DHEAD * DMODEL;      // 1.05M
  char* ws = (char*)d_ws;
  int* mflag            = (int*)ws;                       ws += 16;
  unsigned short* h_bf  = (unsigned short*)ws;            ws += E * 2;
  unsigned short* wq_bf = (unsigned short*)ws;            ws += WQ * 2;
  unsigned short* wkv_bf= (unsigned short*)ws;            ws += 2 * WQ * 2;
  unsigned short* wo_bf = (unsigned short*)ws;            ws += WQ * 2;
  unsigned short* Qb    = (unsigned short*)ws;            ws += E * 2;
  unsigned short* Kb    = (unsigned short*)ws;            ws += E * 2;
  unsigned short* Vtb   = (unsigned short*)ws;            ws += E * 2;
  unsigned short* AV    = (unsigned short*)ws;            ws += E * 2;
  float* AO             = (float*)ws;

  const dim3 blk(256);
  detect_mask<<<1, blk, 0, stream>>>(msk, mflag);
  cvt_kernel<<<dim3((int)(E / 1024)), blk, 0, stream>>>(h, h_bf, (int)E);
  cvt_kernel<<<dim3((int)(WQ / 1024)), blk, 0, stream>>>(wq, wq_bf, (int)WQ);
  cvt_kernel<<<dim3((int)(2 * WQ / 1024)), blk, 0, stream>>>(wkv, wkv_bf, (int)(2 * WQ));
  cvt_kernel<<<dim3((int)(WQ / 1024)), blk, 0, stream>>>(wo, wo_bf, (int)WQ);

  gemm_bt<0><<<dim3(DMODEL / 128, T_LEN * BSZ / 128), blk, 0, stream>>>(h_bf, wq_bf, Qb, nullptr, nullptr, DMODEL);
  gemm_bt<1><<<dim3(2 * DMODEL / 128, T_LEN * BSZ / 128), blk, 0, stream>>>(h_bf, wkv_bf, Kb, Vtb, nullptr, DMODEL);
  attn_mfma<<<dim3(T_LEN / 64, BSZ, NHEAD), blk, 0, stream>>>(Qb, Kb, Vtb, msk, mflag, AV);
  gemm_bt<2><<<dim3(DMODEL / 128, T_LEN * BSZ / 128), blk, 0, stream>>>(AV, wo_bf, nullptr, nullptr, AO, DMODEL);
  ln_kernel<<<dim3(T_LEN * BSZ), blk, 0, stream>>>(h, AO, lng, lnb, out);
}

// Round 5
// 419.662 us; speedup vs baseline: 26.0403x; 1.2882x over previous
//
#include <hip/hip_runtime.h>

#define T_LEN 2048
#define BSZ 4
#define NHEAD 16
#define DHEAD 64
#define DMODEL 1024
#define SCALE 0.125f
#define L2E_SCALE (0.125f * 1.44269504f)   // SCALE * log2(e): softmax in exp2 domain
#define ROW 72   // padded LDS row stride in bf16 (16B-aligned rows)

typedef __bf16 bf16x8 __attribute__((ext_vector_type(8)));
typedef float f32x4 __attribute__((ext_vector_type(4)));

__device__ __forceinline__ float bf2f(unsigned short u) {
  union { unsigned int i; float f; } v; v.i = ((unsigned int)u) << 16; return v.f;
}
__device__ __forceinline__ unsigned short f2bf(float f) {
  union { float f; unsigned int i; } v; v.f = f;
  unsigned int r = v.i + 0x7fffu + ((v.i >> 16) & 1u);   // RNE
  return (unsigned short)(r >> 16);
}

typedef __attribute__((address_space(1))) void* gptr_t;
typedef __attribute__((address_space(3))) void* lptr_t;

__device__ __forceinline__ void load_lds16(const void* g, void* l) {
  __builtin_amdgcn_global_load_lds((gptr_t)g, (lptr_t)l, 16, 0, 0);
}

// fp32 -> bf16 elementwise, n multiple of 4
__global__ __launch_bounds__(256) void cvt_kernel(const float* __restrict__ in,
                                                  unsigned short* __restrict__ out, int n) {
  const int i = (blockIdx.x * 256 + threadIdx.x) * 4;
  if (i < n) {
    const float4 v = *(const float4*)(in + i);
    ushort4 o;
    o.x = f2bf(v.x); o.y = f2bf(v.y); o.z = f2bf(v.z); o.w = f2bf(v.w);
    *(ushort4*)(out + i) = o;
  }
}

// mask layout detect: numpy bool (1B) vs int32. int32 => bytes at idx%4!=0 all zero.
__global__ void detect_mask(const unsigned char* __restrict__ mask, int* __restrict__ flag) {
  __shared__ int any;
  if (threadIdx.x == 0) any = 0;
  __syncthreads();
  int acc = 0;
  for (int i = threadIdx.x; i < T_LEN * BSZ; i += 256)
    if ((i & 3) != 0 && mask[i] != 0) acc = 1;
  if (acc) atomicOr(&any, 1);
  __syncthreads();
  if (threadIdx.x == 0) *flag = any ? 0 : 1;   // 1 => int32, 0 => byte
}

// Per-batch order-preserving compaction map: pos[b][j] = compacted slot (or -1),
// nkeys[b] = number of unmasked keys. One block (64 lanes) per batch.
__global__ __launch_bounds__(64) void build_pos(const unsigned char* __restrict__ mask,
                                                const int* __restrict__ mflag,
                                                int* __restrict__ pos, int* __restrict__ nkeys) {
  const int b = blockIdx.x;
  const int lane = threadIdx.x;
  const int mmode = *mflag;
  int run = 0;
  for (int j0 = 0; j0 < T_LEN; j0 += 64) {
    const int j = j0 + lane;
    const int mval = mmode ? ((const int*)mask)[(size_t)j * BSZ + b]
                           : (int)mask[(size_t)j * BSZ + b];
    const int keep = (mval == 0) ? 1 : 0;
    int x = keep;
#pragma unroll
    for (int off = 1; off < 64; off <<= 1) {
      const int y = __shfl_up(x, off, 64);
      if (lane >= off) x += y;
    }
    pos[b * T_LEN + j] = keep ? (run + x - keep) : -1;
    run += __shfl(x, 63, 64);
  }
  if (lane == 0) nkeys[b] = run;
}

// Fused QKV projection: C = h(8192x1024) * [wq; wkv]^T (3072x1024).
// Region by block column: 0=Q scatter, 1=K compacted scatter, 2=V^T compacted scatter.
__global__ __launch_bounds__(256) void gemm_qkv(const unsigned short* __restrict__ A,
                                                const unsigned short* __restrict__ Wq,
                                                const unsigned short* __restrict__ Wkv,
                                                const int* __restrict__ pos,
                                                unsigned short* __restrict__ outQ,
                                                unsigned short* __restrict__ outK,
                                                unsigned short* __restrict__ outVt) {
  __shared__ alignas(16) unsigned short As[128 * 32];
  __shared__ alignas(16) unsigned short Bs[128 * 32];
  const int K = DMODEL;
  const int tid  = threadIdx.x;
  const int lane = tid & 63;
  const int wv   = tid >> 6;
  const int m0 = blockIdx.y * 128;
  const int n0 = blockIdx.x * 128;
  const int wr = (wv >> 1) * 64;
  const int wc = (wv & 1) * 64;
  const int mi   = lane & 15;
  const int quad = lane >> 4;

  f32x4 acc[4][4] = {};

  const int rowq = tid >> 2;
  const int kg   = (tid & 3) * 8;
  const unsigned short* Bsrc = (n0 < DMODEL) ? (Wq + (size_t)n0 * K)
                                             : (Wkv + (size_t)(n0 - DMODEL) * K);
  const unsigned short* Ag0 = A + (size_t)(m0 + rowq) * K + kg;
  const unsigned short* Ag1 = Ag0 + (size_t)64 * K;
  const unsigned short* Bg0 = Bsrc + (size_t)rowq * K + kg;
  const unsigned short* Bg1 = Bg0 + (size_t)64 * K;
  unsigned short* AsW0 = As + wv * 512;
  unsigned short* AsW1 = As + 2048 + wv * 512;
  unsigned short* BsW0 = Bs + wv * 512;
  unsigned short* BsW1 = Bs + 2048 + wv * 512;

  for (int k0 = 0; k0 < K; k0 += 32) {
    load_lds16(Ag0 + k0, AsW0);
    load_lds16(Ag1 + k0, AsW1);
    load_lds16(Bg0 + k0, BsW0);
    load_lds16(Bg1 + k0, BsW1);
    __syncthreads();
    bf16x8 af[4], bfr[4];
#pragma unroll
    for (int rt = 0; rt < 4; rt++)
      af[rt] = *(const bf16x8*)(As + (wr + rt * 16 + mi) * 32 + quad * 8);
#pragma unroll
    for (int ct = 0; ct < 4; ct++)
      bfr[ct] = *(const bf16x8*)(Bs + (wc + ct * 16 + mi) * 32 + quad * 8);
#pragma unroll
    for (int rt = 0; rt < 4; rt++)
#pragma unroll
      for (int ct = 0; ct < 4; ct++)
        acc[rt][ct] = __builtin_amdgcn_mfma_f32_16x16x32_bf16(af[rt], bfr[ct], acc[rt][ct], 0, 0, 0);
    __syncthreads();
  }

  const int region = n0 >> 10;  // uniform per block
#pragma unroll
  for (int rt = 0; rt < 4; rt++) {
#pragma unroll
    for (int r = 0; r < 4; r++) {
      const int gm = m0 + wr + rt * 16 + quad * 4 + r;
      const int i = gm >> 2, b = gm & 3;
      int p = i;
      if (region > 0) p = pos[b * T_LEN + i];
      if (region > 0 && p < 0) continue;   // masked key: drop
#pragma unroll
      for (int ct = 0; ct < 4; ct++) {
        const int gn = n0 + wc + ct * 16 + mi;
        const int gnl = gn & (DMODEL - 1);
        const int hn = gnl >> 6, d = gnl & 63;
        const float v = acc[rt][ct][r];
        if (region == 0)
          outQ[(((size_t)b * NHEAD + hn) * T_LEN + i) * DHEAD + d] = f2bf(v);
        else if (region == 1)
          outK[(((size_t)b * NHEAD + hn) * T_LEN + p) * DHEAD + d] = f2bf(v);
        else
          outVt[(((size_t)b * NHEAD + hn) * DHEAD + d) * T_LEN + p] = f2bf(v);
      }
    }
  }
}

// Output projection: C = AV(8192x1024) * wo^T -> fp32 AO
__global__ __launch_bounds__(256) void gemm_out(const unsigned short* __restrict__ A,
                                                const unsigned short* __restrict__ Bw,
                                                float* __restrict__ outF) {
  __shared__ alignas(16) unsigned short As[128 * 32];
  __shared__ alignas(16) unsigned short Bs[128 * 32];
  const int K = DMODEL;
  const int tid  = threadIdx.x;
  const int lane = tid & 63;
  const int wv   = tid >> 6;
  const int m0 = blockIdx.y * 128;
  const int n0 = blockIdx.x * 128;
  const int wr = (wv >> 1) * 64;
  const int wc = (wv & 1) * 64;
  const int mi   = lane & 15;
  const int quad = lane >> 4;

  f32x4 acc[4][4] = {};

  const int rowq = tid >> 2;
  const int kg   = (tid & 3) * 8;
  const unsigned short* Ag0 = A  + (size_t)(m0 + rowq) * K + kg;
  const unsigned short* Ag1 = Ag0 + (size_t)64 * K;
  const unsigned short* Bg0 = Bw + (size_t)(n0 + rowq) * K + kg;
  const unsigned short* Bg1 = Bg0 + (size_t)64 * K;
  unsigned short* AsW0 = As + wv * 512;
  unsigned short* AsW1 = As + 2048 + wv * 512;
  unsigned short* BsW0 = Bs + wv * 512;
  unsigned short* BsW1 = Bs + 2048 + wv * 512;

  for (int k0 = 0; k0 < K; k0 += 32) {
    load_lds16(Ag0 + k0, AsW0);
    load_lds16(Ag1 + k0, AsW1);
    load_lds16(Bg0 + k0, BsW0);
    load_lds16(Bg1 + k0, BsW1);
    __syncthreads();
    bf16x8 af[4], bfr[4];
#pragma unroll
    for (int rt = 0; rt < 4; rt++)
      af[rt] = *(const bf16x8*)(As + (wr + rt * 16 + mi) * 32 + quad * 8);
#pragma unroll
    for (int ct = 0; ct < 4; ct++)
      bfr[ct] = *(const bf16x8*)(Bs + (wc + ct * 16 + mi) * 32 + quad * 8);
#pragma unroll
    for (int rt = 0; rt < 4; rt++)
#pragma unroll
      for (int ct = 0; ct < 4; ct++)
        acc[rt][ct] = __builtin_amdgcn_mfma_f32_16x16x32_bf16(af[rt], bfr[ct], acc[rt][ct], 0, 0, 0);
    __syncthreads();
  }

#pragma unroll
  for (int rt = 0; rt < 4; rt++)
#pragma unroll
    for (int ct = 0; ct < 4; ct++)
#pragma unroll
      for (int r = 0; r < 4; r++) {
        const int gm = m0 + wr + rt * 16 + quad * 4 + r;
        const int gn = n0 + wc + ct * 16 + mi;
        outF[(size_t)gm * DMODEL + gn] = acc[rt][ct][r];
      }
}

// MFMA flash attention over COMPACTED keys. grid (T/64, B, NH), 4 waves x 16 q-rows.
__global__ __launch_bounds__(256) void attn_mfma(const unsigned short* __restrict__ Qg,
                                                 const unsigned short* __restrict__ Kg,
                                                 const unsigned short* __restrict__ Vtg,
                                                 const int* __restrict__ nkeys,
                                                 unsigned short* __restrict__ av) {
  __shared__ alignas(16) unsigned short smem[13824];
  unsigned short* Ks  = smem;
  unsigned short* Vts = smem + 4608;
  unsigned short* Qs  = smem + 9216;   // aliased with Ps after qa frags are loaded
  unsigned short* Ps  = smem + 9216;

  const int tid  = threadIdx.x;
  const int lane = tid & 63;
  const int wv   = tid >> 6;
  const int mi   = lane & 15;
  const int quad = lane >> 4;
  const int i0 = blockIdx.x * 64;
  const int b  = blockIdx.y;
  const int n  = blockIdx.z;
  const size_t base = ((size_t)b * NHEAD + n) * T_LEN * DHEAD;
  const int nk = nkeys[b];

  for (int it = tid; it < 512; it += 256) {
    const int r = it >> 3, c8 = (it & 7) * 8;
    *(uint4*)(Qs + r * ROW + c8) = *(const uint4*)(Qg + base + (size_t)(i0 + r) * DHEAD + c8);
  }
  __syncthreads();
  bf16x8 qa[2];
  qa[0] = *(const bf16x8*)(Qs + (wv * 16 + mi) * ROW + quad * 8);
  qa[1] = *(const bf16x8*)(Qs + (wv * 16 + mi) * ROW + 32 + quad * 8);

  float m_st[4], l_st[4];
  f32x4 oc[4] = {};
#pragma unroll
  for (int r = 0; r < 4; r++) { m_st[r] = -1e30f; l_st[r] = 0.f; }

  unsigned short* PsW = Ps + wv * 1152;   // 16*ROW per wave

  for (int j0 = 0; j0 < nk; j0 += 64) {
    for (int it = tid; it < 512; it += 256) {
      const int r = it >> 3, c8 = (it & 7) * 8;
      *(uint4*)(Ks  + r * ROW + c8) = *(const uint4*)(Kg  + base + (size_t)(j0 + r) * DHEAD + c8);
      *(uint4*)(Vts + r * ROW + c8) = *(const uint4*)(Vtg + base + (size_t)r * T_LEN + j0 + c8);
    }
    __syncthreads();

    f32x4 sc[4] = {};
#pragma unroll
    for (int ct = 0; ct < 4; ct++) {
      const bf16x8 kf0 = *(const bf16x8*)(Ks + (ct * 16 + mi) * ROW + quad * 8);
      const bf16x8 kf1 = *(const bf16x8*)(Ks + (ct * 16 + mi) * ROW + 32 + quad * 8);
      sc[ct] = __builtin_amdgcn_mfma_f32_16x16x32_bf16(qa[0], kf0, sc[ct], 0, 0, 0);
      sc[ct] = __builtin_amdgcn_mfma_f32_16x16x32_bf16(qa[1], kf1, sc[ct], 0, 0, 0);
    }
    bool mk[4];
#pragma unroll
    for (int ct = 0; ct < 4; ct++) mk[ct] = (j0 + ct * 16 + mi >= nk);  // tail only
#pragma unroll
    for (int ct = 0; ct < 4; ct++)
#pragma unroll
      for (int r = 0; r < 4; r++)
        sc[ct][r] = mk[ct] ? -1e30f : sc[ct][r] * L2E_SCALE;   // exp2 domain

    float mnew[4], alpha[4], rs[4];
#pragma unroll
    for (int r = 0; r < 4; r++) {
      float v = fmaxf(fmaxf(sc[0][r], sc[1][r]), fmaxf(sc[2][r], sc[3][r]));
      v = fmaxf(v, __shfl_xor(v, 1, 64));
      v = fmaxf(v, __shfl_xor(v, 2, 64));
      v = fmaxf(v, __shfl_xor(v, 4, 64));
      v = fmaxf(v, __shfl_xor(v, 8, 64));
      mnew[r] = fmaxf(m_st[r], v);
      alpha[r] = __builtin_amdgcn_exp2f(m_st[r] - mnew[r]);
      m_st[r] = mnew[r];
      rs[r] = 0.f;
    }
#pragma unroll
    for (int ct = 0; ct < 4; ct++)
#pragma unroll
      for (int r = 0; r < 4; r++) {
        const float p = mk[ct] ? 0.f : __builtin_amdgcn_exp2f(sc[ct][r] - mnew[r]);
        sc[ct][r] = p;
        rs[r] += p;
      }
#pragma unroll
    for (int r = 0; r < 4; r++) {
      float s = rs[r];
      s += __shfl_xor(s, 1, 64);
      s += __shfl_xor(s, 2, 64);
      s += __shfl_xor(s, 4, 64);
      s += __shfl_xor(s, 8, 64);
      l_st[r] = l_st[r] * alpha[r] + s;
    }
#pragma unroll
    for (int ct = 0; ct < 4; ct++)
#pragma unroll
      for (int r = 0; r < 4; r++)
        PsW[(quad * 4 + r) * ROW + ct * 16 + mi] = f2bf(sc[ct][r]);
#pragma unroll
    for (int ct = 0; ct < 4; ct++)
#pragma unroll
      for (int r = 0; r < 4; r++)
        oc[ct][r] *= alpha[r];
    const bf16x8 pa0 = *(const bf16x8*)(PsW + mi * ROW + quad * 8);
    const bf16x8 pa1 = *(const bf16x8*)(PsW + mi * ROW + 32 + quad * 8);
#pragma unroll
    for (int ct = 0; ct < 4; ct++) {
      const bf16x8 vf0 = *(const bf16x8*)(Vts + (ct * 16 + mi) * ROW + quad * 8);
      const bf16x8 vf1 = *(const bf16x8*)(Vts + (ct * 16 + mi) * ROW + 32 + quad * 8);
      oc[ct] = __builtin_amdgcn_mfma_f32_16x16x32_bf16(pa0, vf0, oc[ct], 0, 0, 0);
      oc[ct] = __builtin_amdgcn_mfma_f32_16x16x32_bf16(pa1, vf1, oc[ct], 0, 0, 0);
    }
    __syncthreads();
  }

  float linv[4];
#pragma unroll
  for (int r = 0; r < 4; r++) linv[r] = (l_st[r] > 0.f) ? (1.f / l_st[r]) : 0.f;
#pragma unroll
  for (int ct = 0; ct < 4; ct++)
#pragma unroll
    for (int r = 0; r < 4; r++) {
      const int q = i0 + wv * 16 + quad * 4 + r;
      const int d = ct * 16 + mi;
      av[((size_t)q * BSZ + b) * DMODEL + n * DHEAD + d] = f2bf(oc[ct][r] * linv[r]);
    }
}

// out = LayerNorm(h + attn_out) * g + b  — fp32 in, fp32 out
__global__ __launch_bounds__(256) void ln_kernel(const float* __restrict__ h,
                                                 const float* __restrict__ ao,
                                                 const float* __restrict__ g,
                                                 const float* __restrict__ bb,
                                                 float* __restrict__ out) {
  __shared__ float red[16];
  const int row = blockIdx.x;
  const int tid = threadIdx.x;
  const size_t base = (size_t)row * DMODEL;
  float x[4];
  float s = 0.f, sq = 0.f;
#pragma unroll
  for (int k = 0; k < 4; k++) {
    const int c = tid + k * 256;
    const float xv = h[base + c] + ao[base + c];
    x[k] = xv; s += xv; sq += xv * xv;
  }
#pragma unroll
  for (int off = 32; off; off >>= 1) { s += __shfl_xor(s, off, 64); sq += __shfl_xor(sq, off, 64); }
  const int wv = tid >> 6, lane = tid & 63;
  if (lane == 0) { red[wv] = s; red[8 + wv] = sq; }
  __syncthreads();
  if (tid == 0) {
    float ts = 0.f, tq = 0.f;
    for (int w = 0; w < 4; w++) { ts += red[w]; tq += red[8 + w]; }
    red[4] = ts; red[12] = tq;
  }
  __syncthreads();
  const float mu  = red[4] * (1.f / DMODEL);
  const float var = red[12] * (1.f / DMODEL) - mu * mu;
  const float inv = rsqrtf(var + 1e-5f);
#pragma unroll
  for (int k = 0; k < 4; k++) {
    const int c = tid + k * 256;
    out[base + c] = (x[k] - mu) * inv * g[c] + bb[c];
  }
}

extern "C" void kernel_launch(void* const* d_in, const int* in_sizes, int n_in,
                              void* d_out, int out_size, void* d_ws, size_t ws_size,
                              hipStream_t stream) {
  (void)in_sizes; (void)n_in; (void)out_size; (void)ws_size;
  const float* h           = (const float*)d_in[0];
  const unsigned char* msk = (const unsigned char*)d_in[1];
  const float* wq          = (const float*)d_in[2];
  const float* wkv         = (const float*)d_in[3];
  const float* wo          = (const float*)d_in[4];
  const float* lng         = (const float*)d_in[5];
  const float* lnb         = (const float*)d_in[6];
  float* out = (float*)d_out;

  const size_t E  = (size_t)T_LEN * BSZ * DMODEL;        // 8.39M
  const size_t WQ = (size_t)NHEAD * DHEAD * DMODEL;      // 1.05M
  char* ws = (char*)d_ws;
  int* mflag            = (int*)ws;                       ws += 16;
  int* nkeys            = (int*)ws;                       ws += 16;
  int* pos              = (int*)ws;                       ws += (size_t)BSZ * T_LEN * 4;
  unsigned short* h_bf  = (unsigned short*)ws;            ws += E * 2;
  unsigned short* wq_bf = (unsigned short*)ws;            ws += WQ * 2;
  unsigned short* wkv_bf= (unsigned short*)ws;            ws += 2 * WQ * 2;
  unsigned short* wo_bf = (unsigned short*)ws;            ws += WQ * 2;
  unsigned short* Qb    = (unsigned short*)ws;            ws += E * 2;
  unsigned short* Kb    = (unsigned short*)ws;            ws += E * 2;
  unsigned short* Vtb   = (unsigned short*)ws;            ws += E * 2;
  unsigned short* AV    = (unsigned short*)ws;            ws += E * 2;
  float* AO             = (float*)ws;

  const dim3 blk(256);
  detect_mask<<<1, blk, 0, stream>>>(msk, mflag);
  build_pos<<<dim3(BSZ), dim3(64), 0, stream>>>(msk, mflag, pos, nkeys);
  cvt_kernel<<<dim3((int)(E / 1024)), blk, 0, stream>>>(h, h_bf, (int)E);
  cvt_kernel<<<dim3((int)(WQ / 1024)), blk, 0, stream>>>(wq, wq_bf, (int)WQ);
  cvt_kernel<<<dim3((int)(2 * WQ / 1024)), blk, 0, stream>>>(wkv, wkv_bf, (int)(2 * WQ));
  cvt_kernel<<<dim3((int)(WQ / 1024)), blk, 0, stream>>>(wo, wo_bf, (int)WQ);

  gemm_qkv<<<dim3(3 * DMODEL / 128, T_LEN * BSZ / 128), blk, 0, stream>>>(
      h_bf, wq_bf, wkv_bf, pos, Qb, Kb, Vtb);
  attn_mfma<<<dim3(T_LEN / 64, BSZ, NHEAD), blk, 0, stream>>>(Qb, Kb, Vtb, nkeys, AV);
  gemm_out<<<dim3(DMODEL / 128, T_LEN * BSZ / 128), blk, 0, stream>>>(AV, wo_bf, AO);
  ln_kernel<<<dim3(T_LEN * BSZ), blk, 0, stream>>>(h, AO, lng, lnb, out);
}

// Round 6
// 341.567 us; speedup vs baseline: 31.9940x; 1.2286x over previous
//
#include <hip/hip_runtime.h>

#define T_LEN 2048
#define BSZ 4
#define NHEAD 16
#define DHEAD 64
#define DMODEL 1024
#define SCALE 0.125f
#define L2E_SCALE (0.125f * 1.44269504f)   // SCALE*log2(e): folded into Q at projection
#define ROW 72   // padded LDS row stride in bf16 (16B-aligned rows)

typedef __bf16 bf16x8 __attribute__((ext_vector_type(8)));
typedef float f32x4 __attribute__((ext_vector_type(4)));

__device__ __forceinline__ float bf2f(unsigned short u) {
  union { unsigned int i; float f; } v; v.i = ((unsigned int)u) << 16; return v.f;
}
__device__ __forceinline__ unsigned short f2bf(float f) {
  union { float f; unsigned int i; } v; v.f = f;
  unsigned int r = v.i + 0x7fffu + ((v.i >> 16) & 1u);   // RNE
  return (unsigned short)(r >> 16);
}

typedef __attribute__((address_space(1))) void* gptr_t;
typedef __attribute__((address_space(3))) void* lptr_t;

__device__ __forceinline__ void load_lds16(const void* g, void* l) {
  __builtin_amdgcn_global_load_lds((gptr_t)g, (lptr_t)l, 16, 0, 0);
}

// ---- prep: mask-layout detect + per-batch compaction map, one block ----
__global__ __launch_bounds__(256) void prep_kernel(const unsigned char* __restrict__ mask,
                                                   int* __restrict__ pos,
                                                   int* __restrict__ nkeys) {
  __shared__ int s_any;
  const int tid = threadIdx.x;
  if (tid == 0) s_any = 0;
  __syncthreads();
  int acc = 0;
  for (int i = tid; i < T_LEN * BSZ; i += 256)
    if ((i & 3) != 0 && mask[i] != 0) acc = 1;
  if (acc) atomicOr(&s_any, 1);
  __syncthreads();
  const int mmode = s_any ? 0 : 1;   // 1 => int32 layout, 0 => byte layout
  const int wv = tid >> 6, lane = tid & 63;
  const int b = wv;                  // wave b handles batch b
  int run = 0;
  for (int j0 = 0; j0 < T_LEN; j0 += 64) {
    const int j = j0 + lane;
    const int mval = mmode ? ((const int*)mask)[(size_t)j * BSZ + b]
                           : (int)mask[(size_t)j * BSZ + b];
    const int keep = (mval == 0) ? 1 : 0;
    int x = keep;
#pragma unroll
    for (int off = 1; off < 64; off <<= 1) {
      const int y = __shfl_up(x, off, 64);
      if (lane >= off) x += y;
    }
    pos[b * T_LEN + j] = keep ? (run + x - keep) : -1;
    run += __shfl(x, 63, 64);
  }
  if (lane == 0) nkeys[b] = run;
}

// ---- single fp32->bf16 conversion pass over h, wq, wkv, wo ----
__global__ __launch_bounds__(256) void cvt_all(const float* __restrict__ h,
                                               const float* __restrict__ wq,
                                               const float* __restrict__ wkv,
                                               const float* __restrict__ wo,
                                               unsigned short* __restrict__ h_bf,
                                               unsigned short* __restrict__ wq_bf,
                                               unsigned short* __restrict__ wkv_bf,
                                               unsigned short* __restrict__ wo_bf) {
  const size_t E4 = (size_t)T_LEN * BSZ * DMODEL / 4;   // 2097152 groups
  const size_t W4 = (size_t)NHEAD * DHEAD * DMODEL / 4; // 262144 groups
  const size_t g = (size_t)blockIdx.x * 256 + threadIdx.x;
  const float* src; unsigned short* dst; size_t off;
  if (g < E4)                { src = h;   dst = h_bf;   off = g; }
  else if (g < E4 + W4)      { src = wq;  dst = wq_bf;  off = g - E4; }
  else if (g < E4 + 3 * W4)  { src = wkv; dst = wkv_bf; off = g - E4 - W4; }
  else                       { src = wo;  dst = wo_bf;  off = g - E4 - 3 * W4; }
  const float4 v = *(const float4*)(src + off * 4);
  ushort4 o;
  o.x = f2bf(v.x); o.y = f2bf(v.y); o.z = f2bf(v.z); o.w = f2bf(v.w);
  *(ushort4*)(dst + off * 4) = o;
}

// ---- fused QKV projection; Q prescaled by L2E_SCALE; K/V^T compacted ----
__global__ __launch_bounds__(256) void gemm_qkv(const unsigned short* __restrict__ A,
                                                const unsigned short* __restrict__ Wq,
                                                const unsigned short* __restrict__ Wkv,
                                                const int* __restrict__ pos,
                                                unsigned short* __restrict__ outQ,
                                                unsigned short* __restrict__ outK,
                                                unsigned short* __restrict__ outVt) {
  __shared__ alignas(16) unsigned short As[128 * 32];
  __shared__ alignas(16) unsigned short Bs[128 * 32];
  const int K = DMODEL;
  const int tid  = threadIdx.x;
  const int lane = tid & 63;
  const int wv   = tid >> 6;
  const int m0 = blockIdx.y * 128;
  const int n0 = blockIdx.x * 128;
  const int wr = (wv >> 1) * 64;
  const int wc = (wv & 1) * 64;
  const int mi   = lane & 15;
  const int quad = lane >> 4;

  f32x4 acc[4][4] = {};

  const int rowq = tid >> 2;
  const int kg   = (tid & 3) * 8;
  const unsigned short* Bsrc = (n0 < DMODEL) ? (Wq + (size_t)n0 * K)
                                             : (Wkv + (size_t)(n0 - DMODEL) * K);
  const unsigned short* Ag0 = A + (size_t)(m0 + rowq) * K + kg;
  const unsigned short* Ag1 = Ag0 + (size_t)64 * K;
  const unsigned short* Bg0 = Bsrc + (size_t)rowq * K + kg;
  const unsigned short* Bg1 = Bg0 + (size_t)64 * K;
  unsigned short* AsW0 = As + wv * 512;
  unsigned short* AsW1 = As + 2048 + wv * 512;
  unsigned short* BsW0 = Bs + wv * 512;
  unsigned short* BsW1 = Bs + 2048 + wv * 512;

  for (int k0 = 0; k0 < K; k0 += 32) {
    load_lds16(Ag0 + k0, AsW0);
    load_lds16(Ag1 + k0, AsW1);
    load_lds16(Bg0 + k0, BsW0);
    load_lds16(Bg1 + k0, BsW1);
    __syncthreads();
    bf16x8 af[4], bfr[4];
#pragma unroll
    for (int rt = 0; rt < 4; rt++)
      af[rt] = *(const bf16x8*)(As + (wr + rt * 16 + mi) * 32 + quad * 8);
#pragma unroll
    for (int ct = 0; ct < 4; ct++)
      bfr[ct] = *(const bf16x8*)(Bs + (wc + ct * 16 + mi) * 32 + quad * 8);
#pragma unroll
    for (int rt = 0; rt < 4; rt++)
#pragma unroll
      for (int ct = 0; ct < 4; ct++)
        acc[rt][ct] = __builtin_amdgcn_mfma_f32_16x16x32_bf16(af[rt], bfr[ct], acc[rt][ct], 0, 0, 0);
    __syncthreads();
  }

  const int region = n0 >> 10;  // uniform per block
#pragma unroll
  for (int rt = 0; rt < 4; rt++) {
#pragma unroll
    for (int r = 0; r < 4; r++) {
      const int gm = m0 + wr + rt * 16 + quad * 4 + r;
      const int i = gm >> 2, b = gm & 3;
      int p = i;
      if (region > 0) p = pos[b * T_LEN + i];
      if (region > 0 && p < 0) continue;   // masked key: drop
#pragma unroll
      for (int ct = 0; ct < 4; ct++) {
        const int gn = n0 + wc + ct * 16 + mi;
        const int gnl = gn & (DMODEL - 1);
        const int hn = gnl >> 6, d = gnl & 63;
        const float v = acc[rt][ct][r];
        if (region == 0)
          outQ[(((size_t)b * NHEAD + hn) * T_LEN + i) * DHEAD + d] = f2bf(v * L2E_SCALE);
        else if (region == 1)
          outK[(((size_t)b * NHEAD + hn) * T_LEN + p) * DHEAD + d] = f2bf(v);
        else
          outVt[(((size_t)b * NHEAD + hn) * DHEAD + d) * T_LEN + p] = f2bf(v);
      }
    }
  }
}

// ---- output projection: AV(8192x1024) * wo^T -> fp32 AO ----
__global__ __launch_bounds__(256) void gemm_out(const unsigned short* __restrict__ A,
                                                const unsigned short* __restrict__ Bw,
                                                float* __restrict__ outF) {
  __shared__ alignas(16) unsigned short As[128 * 32];
  __shared__ alignas(16) unsigned short Bs[128 * 32];
  const int K = DMODEL;
  const int tid  = threadIdx.x;
  const int lane = tid & 63;
  const int wv   = tid >> 6;
  const int m0 = blockIdx.y * 128;
  const int n0 = blockIdx.x * 128;
  const int wr = (wv >> 1) * 64;
  const int wc = (wv & 1) * 64;
  const int mi   = lane & 15;
  const int quad = lane >> 4;

  f32x4 acc[4][4] = {};

  const int rowq = tid >> 2;
  const int kg   = (tid & 3) * 8;
  const unsigned short* Ag0 = A  + (size_t)(m0 + rowq) * K + kg;
  const unsigned short* Ag1 = Ag0 + (size_t)64 * K;
  const unsigned short* Bg0 = Bw + (size_t)(n0 + rowq) * K + kg;
  const unsigned short* Bg1 = Bg0 + (size_t)64 * K;
  unsigned short* AsW0 = As + wv * 512;
  unsigned short* AsW1 = As + 2048 + wv * 512;
  unsigned short* BsW0 = Bs + wv * 512;
  unsigned short* BsW1 = Bs + 2048 + wv * 512;

  for (int k0 = 0; k0 < K; k0 += 32) {
    load_lds16(Ag0 + k0, AsW0);
    load_lds16(Ag1 + k0, AsW1);
    load_lds16(Bg0 + k0, BsW0);
    load_lds16(Bg1 + k0, BsW1);
    __syncthreads();
    bf16x8 af[4], bfr[4];
#pragma unroll
    for (int rt = 0; rt < 4; rt++)
      af[rt] = *(const bf16x8*)(As + (wr + rt * 16 + mi) * 32 + quad * 8);
#pragma unroll
    for (int ct = 0; ct < 4; ct++)
      bfr[ct] = *(const bf16x8*)(Bs + (wc + ct * 16 + mi) * 32 + quad * 8);
#pragma unroll
    for (int rt = 0; rt < 4; rt++)
#pragma unroll
      for (int ct = 0; ct < 4; ct++)
        acc[rt][ct] = __builtin_amdgcn_mfma_f32_16x16x32_bf16(af[rt], bfr[ct], acc[rt][ct], 0, 0, 0);
    __syncthreads();
  }

#pragma unroll
  for (int rt = 0; rt < 4; rt++)
#pragma unroll
    for (int ct = 0; ct < 4; ct++)
#pragma unroll
      for (int r = 0; r < 4; r++) {
        const int gm = m0 + wr + rt * 16 + quad * 4 + r;
        const int gn = n0 + wc + ct * 16 + mi;
        outF[(size_t)gm * DMODEL + gn] = acc[rt][ct][r];
      }
}

// ---- attention chunk: S^T = K·Q^T (fixed-max exp2), P·V accumulate ----
template<bool TAIL>
__device__ __forceinline__ void attn_chunk(int j0, int nk, int mi, int quad,
    const unsigned short* Ks, const unsigned short* Vts, unsigned short* PsW,
    const bf16x8 (&qb)[2][2], f32x4 (&oc)[2][4], float (&rs)[2]) {
  f32x4 sc[2][4] = {};
#pragma unroll
  for (int ct = 0; ct < 4; ct++) {
    const bf16x8 kf0 = *(const bf16x8*)(Ks + (ct * 16 + mi) * ROW + quad * 8);
    const bf16x8 kf1 = *(const bf16x8*)(Ks + (ct * 16 + mi) * ROW + 32 + quad * 8);
#pragma unroll
    for (int g = 0; g < 2; g++) {
      sc[g][ct] = __builtin_amdgcn_mfma_f32_16x16x32_bf16(kf0, qb[g][0], sc[g][ct], 0, 0, 0);
      sc[g][ct] = __builtin_amdgcn_mfma_f32_16x16x32_bf16(kf1, qb[g][1], sc[g][ct], 0, 0, 0);
    }
  }
#pragma unroll
  for (int g = 0; g < 2; g++)
#pragma unroll
    for (int ct = 0; ct < 4; ct++) {
#pragma unroll
      for (int r = 0; r < 4; r++) {
        float p = __builtin_amdgcn_exp2f(sc[g][ct][r]);
        if (TAIL && (j0 + ct * 16 + quad * 4 + r >= nk)) p = 0.f;
        rs[g] += p;
        sc[g][ct][r] = p;
      }
      union { float f; unsigned u; } c0, c1, c2, c3;
      c0.f = sc[g][ct][0]; c1.f = sc[g][ct][1]; c2.f = sc[g][ct][2]; c3.f = sc[g][ct][3];
      const unsigned pk0 = (c0.u >> 16) | (c1.u & 0xFFFF0000u);   // bf16 trunc pack
      const unsigned pk1 = (c2.u >> 16) | (c3.u & 0xFFFF0000u);
      *(uint2*)(PsW + (g * 16 + mi) * ROW + ct * 16 + quad * 4) = make_uint2(pk0, pk1);
    }
  bf16x8 pa0[2], pa1[2];
#pragma unroll
  for (int g = 0; g < 2; g++) {
    pa0[g] = *(const bf16x8*)(PsW + (g * 16 + mi) * ROW + quad * 8);
    pa1[g] = *(const bf16x8*)(PsW + (g * 16 + mi) * ROW + 32 + quad * 8);
  }
#pragma unroll
  for (int ct = 0; ct < 4; ct++) {
    const bf16x8 vf0 = *(const bf16x8*)(Vts + (ct * 16 + mi) * ROW + quad * 8);
    const bf16x8 vf1 = *(const bf16x8*)(Vts + (ct * 16 + mi) * ROW + 32 + quad * 8);
#pragma unroll
    for (int g = 0; g < 2; g++) {
      oc[g][ct] = __builtin_amdgcn_mfma_f32_16x16x32_bf16(pa0[g], vf0, oc[g][ct], 0, 0, 0);
      oc[g][ct] = __builtin_amdgcn_mfma_f32_16x16x32_bf16(pa1[g], vf1, oc[g][ct], 0, 0, 0);
    }
  }
}

// grid (T/128, B, NH), 256 thr = 4 waves x 32 q-rows (2 groups of 16)
__global__ __launch_bounds__(256, 4) void attn_mfma(const unsigned short* __restrict__ Qg,
                                                    const unsigned short* __restrict__ Kg,
                                                    const unsigned short* __restrict__ Vtg,
                                                    const int* __restrict__ nkeys,
                                                    unsigned short* __restrict__ av) {
  // ushorts: Ks[0,4608) Vts[4608,9216) Qs/Ps[9216,18432) Ls(f32x128)@18432
  __shared__ alignas(16) unsigned short smem[18688];
  unsigned short* Ks  = smem;
  unsigned short* Vts = smem + 4608;
  unsigned short* Qs  = smem + 9216;
  float* Ls = (float*)(smem + 18432);

  const int tid  = threadIdx.x;
  const int lane = tid & 63;
  const int wv   = tid >> 6;
  const int mi   = lane & 15;
  const int quad = lane >> 4;
  const int i0 = blockIdx.x * 128;
  const int b  = blockIdx.y;
  const int n  = blockIdx.z;
  const size_t base = ((size_t)b * NHEAD + n) * T_LEN * DHEAD;
  const int nk = nkeys[b];

  for (int it = tid; it < 1024; it += 256) {
    const int r = it >> 3, c8 = (it & 7) * 8;
    *(uint4*)(Qs + r * ROW + c8) = *(const uint4*)(Qg + base + (size_t)(i0 + r) * DHEAD + c8);
  }
  __syncthreads();
  bf16x8 qb[2][2];
#pragma unroll
  for (int g = 0; g < 2; g++) {
    qb[g][0] = *(const bf16x8*)(Qs + (wv * 32 + g * 16 + mi) * ROW + quad * 8);
    qb[g][1] = *(const bf16x8*)(Qs + (wv * 32 + g * 16 + mi) * ROW + 32 + quad * 8);
  }

  f32x4 oc[2][4] = {};
  float rs[2] = {0.f, 0.f};
  unsigned short* PsW = Qs + wv * 2304;   // 32*ROW per wave (aliases Qs; safe after barrier)

  const int nmain = nk & ~63;
  for (int j0 = 0; j0 < nmain; j0 += 64) {
    for (int it = tid; it < 512; it += 256) {
      const int r = it >> 3, c8 = (it & 7) * 8;
      *(uint4*)(Ks  + r * ROW + c8) = *(const uint4*)(Kg  + base + (size_t)(j0 + r) * DHEAD + c8);
      *(uint4*)(Vts + r * ROW + c8) = *(const uint4*)(Vtg + base + (size_t)r * T_LEN + j0 + c8);
    }
    __syncthreads();
    attn_chunk<false>(j0, nk, mi, quad, Ks, Vts, PsW, qb, oc, rs);
    __syncthreads();
  }
  if (nmain < nk) {
    for (int it = tid; it < 512; it += 256) {
      const int r = it >> 3, c8 = (it & 7) * 8;
      *(uint4*)(Ks  + r * ROW + c8) = *(const uint4*)(Kg  + base + (size_t)(nmain + r) * DHEAD + c8);
      *(uint4*)(Vts + r * ROW + c8) = *(const uint4*)(Vtg + base + (size_t)r * T_LEN + nmain + c8);
    }
    __syncthreads();
    attn_chunk<true>(nmain, nk, mi, quad, Ks, Vts, PsW, qb, oc, rs);
  }

  // final l reduction: lane's rs[g] is partial sum for q=mi over its quad's keys
#pragma unroll
  for (int g = 0; g < 2; g++) {
    float t = rs[g];
    t += __shfl_xor(t, 16, 64);
    t += __shfl_xor(t, 32, 64);
    rs[g] = t;
  }
  if (quad == 0) { Ls[wv * 32 + mi] = rs[0]; Ls[wv * 32 + 16 + mi] = rs[1]; }
  __syncthreads();
  float linv[2][4];
#pragma unroll
  for (int g = 0; g < 2; g++)
#pragma unroll
    for (int r = 0; r < 4; r++) {
      const float l = Ls[wv * 32 + g * 16 + quad * 4 + r];
      linv[g][r] = (l > 0.f) ? (1.f / l) : 0.f;
    }
#pragma unroll
  for (int g = 0; g < 2; g++)
#pragma unroll
    for (int ct = 0; ct < 4; ct++)
#pragma unroll
      for (int r = 0; r < 4; r++) {
        const int q = i0 + wv * 32 + g * 16 + quad * 4 + r;
        const int d = ct * 16 + mi;
        av[((size_t)q * BSZ + b) * DMODEL + n * DHEAD + d] = f2bf(oc[g][ct][r] * linv[g][r]);
      }
}

// ---- out = LayerNorm(h + attn_out)*g + b ----
__global__ __launch_bounds__(256) void ln_kernel(const float* __restrict__ h,
                                                 const float* __restrict__ ao,
                                                 const float* __restrict__ g,
                                                 const float* __restrict__ bb,
                                                 float* __restrict__ out) {
  __shared__ float red[16];
  const int row = blockIdx.x;
  const int tid = threadIdx.x;
  const size_t base = (size_t)row * DMODEL;
  float x[4];
  float s = 0.f, sq = 0.f;
#pragma unroll
  for (int k = 0; k < 4; k++) {
    const int c = tid + k * 256;
    const float xv = h[base + c] + ao[base + c];
    x[k] = xv; s += xv; sq += xv * xv;
  }
#pragma unroll
  for (int off = 32; off; off >>= 1) { s += __shfl_xor(s, off, 64); sq += __shfl_xor(sq, off, 64); }
  const int wv = tid >> 6, lane = tid & 63;
  if (lane == 0) { red[wv] = s; red[8 + wv] = sq; }
  __syncthreads();
  if (tid == 0) {
    float ts = 0.f, tq = 0.f;
    for (int w = 0; w < 4; w++) { ts += red[w]; tq += red[8 + w]; }
    red[4] = ts; red[12] = tq;
  }
  __syncthreads();
  const float mu  = red[4] * (1.f / DMODEL);
  const float var = red[12] * (1.f / DMODEL) - mu * mu;
  const float inv = rsqrtf(var + 1e-5f);
#pragma unroll
  for (int k = 0; k < 4; k++) {
    const int c = tid + k * 256;
    out[base + c] = (x[k] - mu) * inv * g[c] + bb[c];
  }
}

extern "C" void kernel_launch(void* const* d_in, const int* in_sizes, int n_in,
                              void* d_out, int out_size, void* d_ws, size_t ws_size,
                              hipStream_t stream) {
  (void)in_sizes; (void)n_in; (void)out_size; (void)ws_size;
  const float* h           = (const float*)d_in[0];
  const unsigned char* msk = (const unsigned char*)d_in[1];
  const float* wq          = (const float*)d_in[2];
  const float* wkv         = (const float*)d_in[3];
  const float* wo          = (const float*)d_in[4];
  const float* lng         = (const float*)d_in[5];
  const float* lnb         = (const float*)d_in[6];
  float* out = (float*)d_out;

  const size_t E  = (size_t)T_LEN * BSZ * DMODEL;        // 8.39M
  const size_t WQ = (size_t)NHEAD * DHEAD * DMODEL;      // 1.05M
  char* ws = (char*)d_ws;
  int* nkeys            = (int*)ws;                       ws += 16;
  int* pos              = (int*)ws;                       ws += (size_t)BSZ * T_LEN * 4;
  unsigned short* h_bf  = (unsigned short*)ws;            ws += E * 2;
  unsigned short* wq_bf = (unsigned short*)ws;            ws += WQ * 2;
  unsigned short* wkv_bf= (unsigned short*)ws;            ws += 2 * WQ * 2;
  unsigned short* wo_bf = (unsigned short*)ws;            ws += WQ * 2;
  unsigned short* Qb    = (unsigned short*)ws;            ws += E * 2;
  unsigned short* Kb    = (unsigned short*)ws;            ws += E * 2;
  unsigned short* Vtb   = (unsigned short*)ws;            ws += E * 2;
  unsigned short* AV    = (unsigned short*)ws;            ws += E * 2;
  float* AO             = (float*)ws;

  const dim3 blk(256);
  prep_kernel<<<1, blk, 0, stream>>>(msk, pos, nkeys);
  cvt_all<<<dim3(12288), blk, 0, stream>>>(h, wq, wkv, wo, h_bf, wq_bf, wkv_bf, wo_bf);
  gemm_qkv<<<dim3(3 * DMODEL / 128, T_LEN * BSZ / 128), blk, 0, stream>>>(
      h_bf, wq_bf, wkv_bf, pos, Qb, Kb, Vtb);
  attn_mfma<<<dim3(T_LEN / 128, BSZ, NHEAD), blk, 0, stream>>>(Qb, Kb, Vtb, nkeys, AV);
  gemm_out<<<dim3(DMODEL / 128, T_LEN * BSZ / 128), blk, 0, stream>>>(AV, wo_bf, AO);
  ln_kernel<<<dim3(T_LEN * BSZ), blk, 0, stream>>>(h, AO, lng, lnb, out);
}

// Round 7
// 319.869 us; speedup vs baseline: 34.1643x; 1.0678x over previous
//
#include <hip/hip_runtime.h>

#define T_LEN 2048
#define BSZ 4
#define NHEAD 16
#define DHEAD 64
#define DMODEL 1024
#define SCALE 0.125f
#define L2E_SCALE (0.125f * 1.44269504f)   // SCALE*log2(e): folded into Q at projection
#define ROW 72   // padded LDS row stride in bf16 (attn kernel)

typedef __bf16 bf16x8 __attribute__((ext_vector_type(8)));
typedef float f32x4 __attribute__((ext_vector_type(4)));

__device__ __forceinline__ float bf2f(unsigned short u) {
  union { unsigned int i; float f; } v; v.i = ((unsigned int)u) << 16; return v.f;
}
__device__ __forceinline__ unsigned short f2bf(float f) {
  union { float f; unsigned int i; } v; v.f = f;
  unsigned int r = v.i + 0x7fffu + ((v.i >> 16) & 1u);   // RNE
  return (unsigned short)(r >> 16);
}

typedef __attribute__((address_space(1))) void* gptr_t;
typedef __attribute__((address_space(3))) void* lptr_t;

__device__ __forceinline__ void load_lds16(const void* g, void* l) {
  __builtin_amdgcn_global_load_lds((gptr_t)g, (lptr_t)l, 16, 0, 0);
}

// ---- fused fp32->bf16 conversion (blocks 0..12287) + mask prep (block 12288) ----
__global__ __launch_bounds__(256) void cvt_prep(const float* __restrict__ h,
                                                const float* __restrict__ wq,
                                                const float* __restrict__ wkv,
                                                const float* __restrict__ wo,
                                                const unsigned char* __restrict__ mask,
                                                unsigned short* __restrict__ h_bf,
                                                unsigned short* __restrict__ wq_bf,
                                                unsigned short* __restrict__ wkv_bf,
                                                unsigned short* __restrict__ wo_bf,
                                                int* __restrict__ pos,
                                                int* __restrict__ nkeys) {
  const int tid = threadIdx.x;
  if (blockIdx.x < 12288) {
    const size_t E4 = (size_t)T_LEN * BSZ * DMODEL / 4;
    const size_t W4 = (size_t)NHEAD * DHEAD * DMODEL / 4;
    const size_t g = (size_t)blockIdx.x * 256 + tid;
    const float* src; unsigned short* dst; size_t off;
    if (g < E4)                { src = h;   dst = h_bf;   off = g; }
    else if (g < E4 + W4)      { src = wq;  dst = wq_bf;  off = g - E4; }
    else if (g < E4 + 3 * W4)  { src = wkv; dst = wkv_bf; off = g - E4 - W4; }
    else                       { src = wo;  dst = wo_bf;  off = g - E4 - 3 * W4; }
    const float4 v = *(const float4*)(src + off * 4);
    ushort4 o;
    o.x = f2bf(v.x); o.y = f2bf(v.y); o.z = f2bf(v.z); o.w = f2bf(v.w);
    *(ushort4*)(dst + off * 4) = o;
    return;
  }
  // ---- prep block: mask-layout detect + per-batch compaction scan ----
  __shared__ int s_any;
  if (tid == 0) s_any = 0;
  __syncthreads();
  int acc = 0;
  for (int i = tid; i < T_LEN * BSZ; i += 256)
    if ((i & 3) != 0 && mask[i] != 0) acc = 1;
  if (acc) atomicOr(&s_any, 1);
  __syncthreads();
  const int mmode = s_any ? 0 : 1;   // 1 => int32 layout, 0 => byte layout
  const int wv = tid >> 6, lane = tid & 63;
  const int b = wv;
  int run = 0;
  for (int j0 = 0; j0 < T_LEN; j0 += 64) {
    const int j = j0 + lane;
    const int mval = mmode ? ((const int*)mask)[(size_t)j * BSZ + b]
                           : (int)mask[(size_t)j * BSZ + b];
    const int keep = (mval == 0) ? 1 : 0;
    int x = keep;
#pragma unroll
    for (int off = 1; off < 64; off <<= 1) {
      const int y = __shfl_up(x, off, 64);
      if (lane >= off) x += y;
    }
    pos[b * T_LEN + j] = keep ? (run + x - keep) : -1;
    run += __shfl(x, 63, 64);
  }
  if (lane == 0) nkeys[b] = run;
}

// ======== BK=64 XOR-swizzled GEMM core (shared by qkv / out) ========
// LDS slot (row, c) holds global 16B-chunk (c ^ (row&7)); frag reads un-swizzle.
// Returns acc[4][4] for the 128x128 tile; As/Bs are 128x64 bf16 (8 KB each x2 = 32 KB).
#define GEMM64_BODY(Aptr, Bptr)                                                        \
  const int tid  = threadIdx.x;                                                        \
  const int lane = tid & 63;                                                           \
  const int wv   = tid >> 6;                                                           \
  const int wr = (wv >> 1) * 64;                                                       \
  const int wc = (wv & 1) * 64;                                                        \
  const int mi   = lane & 15;                                                          \
  const int quad = lane >> 4;                                                          \
  f32x4 acc[4][4] = {};                                                                \
  int rowc[4], colc[4];                                                                \
  _Pragma("unroll")                                                                    \
  for (int c = 0; c < 4; c++) {                                                        \
    const int s = c * 256 + tid;                                                       \
    rowc[c] = s >> 3;                                                                  \
    colc[c] = ((s & 7) ^ (rowc[c] & 7)) * 8;                                           \
  }                                                                                    \
  const int swz = mi & 7;                                                              \
  for (int k0 = 0; k0 < DMODEL; k0 += 64) {                                            \
    _Pragma("unroll")                                                                  \
    for (int c = 0; c < 4; c++) {                                                      \
      load_lds16(Aptr + (size_t)rowc[c] * DMODEL + k0 + colc[c], As + c * 2048 + wv * 512); \
      load_lds16(Bptr + (size_t)rowc[c] * DMODEL + k0 + colc[c], Bs + c * 2048 + wv * 512); \
    }                                                                                  \
    __syncthreads();                                                                   \
    _Pragma("unroll")                                                                  \
    for (int kq = 0; kq < 2; kq++) {                                                   \
      const int cp = ((kq * 4 + quad) ^ swz) * 8;                                      \
      bf16x8 af[4], bfr[4];                                                            \
      _Pragma("unroll")                                                                \
      for (int rt = 0; rt < 4; rt++)                                                   \
        af[rt] = *(const bf16x8*)(As + (wr + rt * 16 + mi) * 64 + cp);                 \
      _Pragma("unroll")                                                                \
      for (int ct = 0; ct < 4; ct++)                                                   \
        bfr[ct] = *(const bf16x8*)(Bs + (wc + ct * 16 + mi) * 64 + cp);                \
      _Pragma("unroll")                                                                \
      for (int rt = 0; rt < 4; rt++)                                                   \
        _Pragma("unroll")                                                              \
        for (int ct = 0; ct < 4; ct++)                                                 \
          acc[rt][ct] = __builtin_amdgcn_mfma_f32_16x16x32_bf16(af[rt], bfr[ct], acc[rt][ct], 0, 0, 0); \
    }                                                                                  \
    __syncthreads();                                                                   \
  }

// ---- fused QKV projection; Q prescaled by L2E_SCALE; K/V^T compacted ----
__global__ __launch_bounds__(256) void gemm_qkv(const unsigned short* __restrict__ A,
                                                const unsigned short* __restrict__ Wq,
                                                const unsigned short* __restrict__ Wkv,
                                                const int* __restrict__ pos,
                                                unsigned short* __restrict__ outQ,
                                                unsigned short* __restrict__ outK,
                                                unsigned short* __restrict__ outVt) {
  __shared__ alignas(16) unsigned short As[128 * 64];
  __shared__ alignas(16) unsigned short Bs[128 * 64];
  const int m0 = blockIdx.y * 128;
  const int n0 = blockIdx.x * 128;
  const unsigned short* Abase = A + (size_t)m0 * DMODEL;
  const unsigned short* Bbase = (n0 < DMODEL) ? (Wq + (size_t)n0 * DMODEL)
                                              : (Wkv + (size_t)(n0 - DMODEL) * DMODEL);
  GEMM64_BODY(Abase, Bbase)

  const int region = n0 >> 10;  // uniform per block
#pragma unroll
  for (int rt = 0; rt < 4; rt++) {
#pragma unroll
    for (int r = 0; r < 4; r++) {
      const int gm = m0 + wr + rt * 16 + quad * 4 + r;
      const int i = gm >> 2, b = gm & 3;
      int p = i;
      if (region > 0) p = pos[b * T_LEN + i];
      if (region > 0 && p < 0) continue;   // masked key: drop
#pragma unroll
      for (int ct = 0; ct < 4; ct++) {
        const int gn = n0 + wc + ct * 16 + mi;
        const int gnl = gn & (DMODEL - 1);
        const int hn = gnl >> 6, d = gnl & 63;
        const float v = acc[rt][ct][r];
        if (region == 0)
          outQ[(((size_t)b * NHEAD + hn) * T_LEN + i) * DHEAD + d] = f2bf(v * L2E_SCALE);
        else if (region == 1)
          outK[(((size_t)b * NHEAD + hn) * T_LEN + p) * DHEAD + d] = f2bf(v);
        else
          outVt[(((size_t)b * NHEAD + hn) * DHEAD + d) * T_LEN + p] = f2bf(v);
      }
    }
  }
}

// ---- output projection: AV(8192x1024) * wo^T -> bf16 AO ----
__global__ __launch_bounds__(256) void gemm_out(const unsigned short* __restrict__ A,
                                                const unsigned short* __restrict__ Bw,
                                                unsigned short* __restrict__ outB) {
  __shared__ alignas(16) unsigned short As[128 * 64];
  __shared__ alignas(16) unsigned short Bs[128 * 64];
  const int m0 = blockIdx.y * 128;
  const int n0 = blockIdx.x * 128;
  const unsigned short* Abase = A  + (size_t)m0 * DMODEL;
  const unsigned short* Bbase = Bw + (size_t)n0 * DMODEL;
  GEMM64_BODY(Abase, Bbase)

#pragma unroll
  for (int rt = 0; rt < 4; rt++)
#pragma unroll
    for (int ct = 0; ct < 4; ct++)
#pragma unroll
      for (int r = 0; r < 4; r++) {
        const int gm = m0 + wr + rt * 16 + quad * 4 + r;
        const int gn = n0 + wc + ct * 16 + mi;
        outB[(size_t)gm * DMODEL + gn] = f2bf(acc[rt][ct][r]);
      }
}

// ---- attention chunk: S^T = K·Q^T (fixed-max exp2), P·V accumulate ----
template<bool TAIL>
__device__ __forceinline__ void attn_chunk(int j0, int nk, int mi, int quad,
    const unsigned short* Ks, const unsigned short* Vts, unsigned short* PsW,
    const bf16x8 (&qb)[2][2], f32x4 (&oc)[2][4], float (&rs)[2]) {
  f32x4 sc[2][4] = {};
#pragma unroll
  for (int ct = 0; ct < 4; ct++) {
    const bf16x8 kf0 = *(const bf16x8*)(Ks + (ct * 16 + mi) * ROW + quad * 8);
    const bf16x8 kf1 = *(const bf16x8*)(Ks + (ct * 16 + mi) * ROW + 32 + quad * 8);
#pragma unroll
    for (int g = 0; g < 2; g++) {
      sc[g][ct] = __builtin_amdgcn_mfma_f32_16x16x32_bf16(kf0, qb[g][0], sc[g][ct], 0, 0, 0);
      sc[g][ct] = __builtin_amdgcn_mfma_f32_16x16x32_bf16(kf1, qb[g][1], sc[g][ct], 0, 0, 0);
    }
  }
#pragma unroll
  for (int g = 0; g < 2; g++)
#pragma unroll
    for (int ct = 0; ct < 4; ct++) {
#pragma unroll
      for (int r = 0; r < 4; r++) {
        float p = __builtin_amdgcn_exp2f(sc[g][ct][r]);
        if (TAIL && (j0 + ct * 16 + quad * 4 + r >= nk)) p = 0.f;
        rs[g] += p;
        sc[g][ct][r] = p;
      }
      union { float f; unsigned u; } c0, c1, c2, c3;
      c0.f = sc[g][ct][0]; c1.f = sc[g][ct][1]; c2.f = sc[g][ct][2]; c3.f = sc[g][ct][3];
      const unsigned pk0 = (c0.u >> 16) | (c1.u & 0xFFFF0000u);   // bf16 trunc pack
      const unsigned pk1 = (c2.u >> 16) | (c3.u & 0xFFFF0000u);
      *(uint2*)(PsW + (g * 16 + mi) * ROW + ct * 16 + quad * 4) = make_uint2(pk0, pk1);
    }
  bf16x8 pa0[2], pa1[2];
#pragma unroll
  for (int g = 0; g < 2; g++) {
    pa0[g] = *(const bf16x8*)(PsW + (g * 16 + mi) * ROW + quad * 8);
    pa1[g] = *(const bf16x8*)(PsW + (g * 16 + mi) * ROW + 32 + quad * 8);
  }
#pragma unroll
  for (int ct = 0; ct < 4; ct++) {
    const bf16x8 vf0 = *(const bf16x8*)(Vts + (ct * 16 + mi) * ROW + quad * 8);
    const bf16x8 vf1 = *(const bf16x8*)(Vts + (ct * 16 + mi) * ROW + 32 + quad * 8);
#pragma unroll
    for (int g = 0; g < 2; g++) {
      oc[g][ct] = __builtin_amdgcn_mfma_f32_16x16x32_bf16(pa0[g], vf0, oc[g][ct], 0, 0, 0);
      oc[g][ct] = __builtin_amdgcn_mfma_f32_16x16x32_bf16(pa1[g], vf1, oc[g][ct], 0, 0, 0);
    }
  }
}

// grid (T/128, B, NH), 256 thr = 4 waves x 32 q-rows (2 groups of 16)
__global__ __launch_bounds__(256, 4) void attn_mfma(const unsigned short* __restrict__ Qg,
                                                    const unsigned short* __restrict__ Kg,
                                                    const unsigned short* __restrict__ Vtg,
                                                    const int* __restrict__ nkeys,
                                                    unsigned short* __restrict__ av) {
  __shared__ alignas(16) unsigned short smem[18688];
  unsigned short* Ks  = smem;
  unsigned short* Vts = smem + 4608;
  unsigned short* Qs  = smem + 9216;
  float* Ls = (float*)(smem + 18432);

  const int tid  = threadIdx.x;
  const int lane = tid & 63;
  const int wv   = tid >> 6;
  const int mi   = lane & 15;
  const int quad = lane >> 4;
  const int i0 = blockIdx.x * 128;
  const int b  = blockIdx.y;
  const int n  = blockIdx.z;
  const size_t base = ((size_t)b * NHEAD + n) * T_LEN * DHEAD;
  const int nk = nkeys[b];

  for (int it = tid; it < 1024; it += 256) {
    const int r = it >> 3, c8 = (it & 7) * 8;
    *(uint4*)(Qs + r * ROW + c8) = *(const uint4*)(Qg + base + (size_t)(i0 + r) * DHEAD + c8);
  }
  __syncthreads();
  bf16x8 qb[2][2];
#pragma unroll
  for (int g = 0; g < 2; g++) {
    qb[g][0] = *(const bf16x8*)(Qs + (wv * 32 + g * 16 + mi) * ROW + quad * 8);
    qb[g][1] = *(const bf16x8*)(Qs + (wv * 32 + g * 16 + mi) * ROW + 32 + quad * 8);
  }

  f32x4 oc[2][4] = {};
  float rs[2] = {0.f, 0.f};
  unsigned short* PsW = Qs + wv * 2304;   // 32*ROW per wave (aliases Qs; safe after barrier)

  const int nmain = nk & ~63;
  for (int j0 = 0; j0 < nmain; j0 += 64) {
    for (int it = tid; it < 512; it += 256) {
      const int r = it >> 3, c8 = (it & 7) * 8;
      *(uint4*)(Ks  + r * ROW + c8) = *(const uint4*)(Kg  + base + (size_t)(j0 + r) * DHEAD + c8);
      *(uint4*)(Vts + r * ROW + c8) = *(const uint4*)(Vtg + base + (size_t)r * T_LEN + j0 + c8);
    }
    __syncthreads();
    attn_chunk<false>(j0, nk, mi, quad, Ks, Vts, PsW, qb, oc, rs);
    __syncthreads();
  }
  if (nmain < nk) {
    for (int it = tid; it < 512; it += 256) {
      const int r = it >> 3, c8 = (it & 7) * 8;
      *(uint4*)(Ks  + r * ROW + c8) = *(const uint4*)(Kg  + base + (size_t)(nmain + r) * DHEAD + c8);
      *(uint4*)(Vts + r * ROW + c8) = *(const uint4*)(Vtg + base + (size_t)r * T_LEN + nmain + c8);
    }
    __syncthreads();
    attn_chunk<true>(nmain, nk, mi, quad, Ks, Vts, PsW, qb, oc, rs);
  }

#pragma unroll
  for (int g = 0; g < 2; g++) {
    float t = rs[g];
    t += __shfl_xor(t, 16, 64);
    t += __shfl_xor(t, 32, 64);
    rs[g] = t;
  }
  if (quad == 0) { Ls[wv * 32 + mi] = rs[0]; Ls[wv * 32 + 16 + mi] = rs[1]; }
  __syncthreads();
  float linv[2][4];
#pragma unroll
  for (int g = 0; g < 2; g++)
#pragma unroll
    for (int r = 0; r < 4; r++) {
      const float l = Ls[wv * 32 + g * 16 + quad * 4 + r];
      linv[g][r] = (l > 0.f) ? (1.f / l) : 0.f;
    }
#pragma unroll
  for (int g = 0; g < 2; g++)
#pragma unroll
    for (int ct = 0; ct < 4; ct++)
#pragma unroll
      for (int r = 0; r < 4; r++) {
        const int q = i0 + wv * 32 + g * 16 + quad * 4 + r;
        const int d = ct * 16 + mi;
        av[((size_t)q * BSZ + b) * DMODEL + n * DHEAD + d] = f2bf(oc[g][ct][r] * linv[g][r]);
      }
}

// ---- out = LayerNorm(h + attn_out)*g + b  (ao is bf16) ----
__global__ __launch_bounds__(256) void ln_kernel(const float* __restrict__ h,
                                                 const unsigned short* __restrict__ ao,
                                                 const float* __restrict__ g,
                                                 const float* __restrict__ bb,
                                                 float* __restrict__ out) {
  __shared__ float red[16];
  const int row = blockIdx.x;
  const int tid = threadIdx.x;
  const size_t base = (size_t)row * DMODEL;
  float x[4];
  float s = 0.f, sq = 0.f;
#pragma unroll
  for (int k = 0; k < 4; k++) {
    const int c = tid + k * 256;
    const float xv = h[base + c] + bf2f(ao[base + c]);
    x[k] = xv; s += xv; sq += xv * xv;
  }
#pragma unroll
  for (int off = 32; off; off >>= 1) { s += __shfl_xor(s, off, 64); sq += __shfl_xor(sq, off, 64); }
  const int wv = tid >> 6, lane = tid & 63;
  if (lane == 0) { red[wv] = s; red[8 + wv] = sq; }
  __syncthreads();
  if (tid == 0) {
    float ts = 0.f, tq = 0.f;
    for (int w = 0; w < 4; w++) { ts += red[w]; tq += red[8 + w]; }
    red[4] = ts; red[12] = tq;
  }
  __syncthreads();
  const float mu  = red[4] * (1.f / DMODEL);
  const float var = red[12] * (1.f / DMODEL) - mu * mu;
  const float inv = rsqrtf(var + 1e-5f);
#pragma unroll
  for (int k = 0; k < 4; k++) {
    const int c = tid + k * 256;
    out[base + c] = (x[k] - mu) * inv * g[c] + bb[c];
  }
}

extern "C" void kernel_launch(void* const* d_in, const int* in_sizes, int n_in,
                              void* d_out, int out_size, void* d_ws, size_t ws_size,
                              hipStream_t stream) {
  (void)in_sizes; (void)n_in; (void)out_size; (void)ws_size;
  const float* h           = (const float*)d_in[0];
  const unsigned char* msk = (const unsigned char*)d_in[1];
  const float* wq          = (const float*)d_in[2];
  const float* wkv         = (const float*)d_in[3];
  const float* wo          = (const float*)d_in[4];
  const float* lng         = (const float*)d_in[5];
  const float* lnb         = (const float*)d_in[6];
  float* out = (float*)d_out;

  const size_t E  = (size_t)T_LEN * BSZ * DMODEL;        // 8.39M
  const size_t WQ = (size_t)NHEAD * DHEAD * DMODEL;      // 1.05M
  char* ws = (char*)d_ws;
  int* nkeys            = (int*)ws;                       ws += 16;
  int* pos              = (int*)ws;                       ws += (size_t)BSZ * T_LEN * 4;
  unsigned short* h_bf  = (unsigned short*)ws;            ws += E * 2;
  unsigned short* wq_bf = (unsigned short*)ws;            ws += WQ * 2;
  unsigned short* wkv_bf= (unsigned short*)ws;            ws += 2 * WQ * 2;
  unsigned short* wo_bf = (unsigned short*)ws;            ws += WQ * 2;
  unsigned short* Qb    = (unsigned short*)ws;            ws += E * 2;
  unsigned short* Kb    = (unsigned short*)ws;            ws += E * 2;
  unsigned short* Vtb   = (unsigned short*)ws;            ws += E * 2;
  unsigned short* AV    = (unsigned short*)ws;            ws += E * 2;
  unsigned short* AO    = (unsigned short*)ws;

  const dim3 blk(256);
  cvt_prep<<<dim3(12289), blk, 0, stream>>>(h, wq, wkv, wo, msk,
                                            h_bf, wq_bf, wkv_bf, wo_bf, pos, nkeys);
  gemm_qkv<<<dim3(3 * DMODEL / 128, T_LEN * BSZ / 128), blk, 0, stream>>>(
      h_bf, wq_bf, wkv_bf, pos, Qb, Kb, Vtb);
  attn_mfma<<<dim3(T_LEN / 128, BSZ, NHEAD), blk, 0, stream>>>(Qb, Kb, Vtb, nkeys, AV);
  gemm_out<<<dim3(DMODEL / 128, T_LEN * BSZ / 128), blk, 0, stream>>>(AV, wo_bf, AO);
  ln_kernel<<<dim3(T_LEN * BSZ), blk, 0, stream>>>(h, AO, lng, lnb, out);
}